// Round 7
// baseline (245.659 us; speedup 1.0000x reference)
//
#include <hip/hip_runtime.h>
#include <hip/hip_bf16.h>
#include <math.h>

// Problem constants (GAT_66907000537778)
#define NNODES 50000
#define NEDGES 800000
#define FIN 256
#define HID 32
#define HEADS 4
#define OUTS 40
#define HIDDEN 128   // HEADS*HID
#define NPART 4      // scatter partitions (dst ranges); 50000/4 = 12500

typedef __bf16 bf16x8 __attribute__((ext_vector_type(8)));
typedef float  f32x4  __attribute__((ext_vector_type(4)));

// ---------------------------------------------------------------------------
// CSR construction (grouped by dst), 16-bit indices (N < 65536)
// ---------------------------------------------------------------------------
__global__ void k_pack16(const int* __restrict__ src, const int* __restrict__ dst,
                         ushort* __restrict__ src16, ushort* __restrict__ dst16, int n) {
    int i = blockIdx.x * blockDim.x + threadIdx.x;
    if (i < n) {
        src16[i] = (ushort)src[i];
        dst16[i] = (ushort)dst[i];
    }
}

__global__ void k_hist16(const ushort* __restrict__ dst16, int* __restrict__ counts, int n) {
    int i = blockIdx.x * blockDim.x + threadIdx.x;
    if (i < n) atomicAdd(&counts[dst16[i]], 1);
}

__global__ __launch_bounds__(256) void k_scan1(const int* __restrict__ counts,
                                               int* __restrict__ pre,
                                               int* __restrict__ bsum, int n) {
    __shared__ int ws[4];
    int t = threadIdx.x, b = blockIdx.x, i = b * 256 + t;
    int lane = t & 63, w = t >> 6;
    int v = (i < n) ? counts[i] : 0;
    int x = v;
    #pragma unroll
    for (int off = 1; off < 64; off <<= 1) {
        int tt = __shfl_up(x, off);
        if (lane >= off) x += tt;
    }
    if (lane == 63) ws[w] = x;
    __syncthreads();
    int woff = 0;
    #pragma unroll
    for (int k = 0; k < 4; ++k) woff += (k < w) ? ws[k] : 0;
    int excl = x - v + woff;
    if (i < n) pre[i] = excl;
    if (t == 255) bsum[b] = excl + v;
}

__global__ __launch_bounds__(256) void k_scan2(int* __restrict__ bsum,
                                               int* __restrict__ rp_end, int nb) {
    __shared__ int ws[4];
    int t = threadIdx.x;
    int lane = t & 63, w = t >> 6;
    int v = (t < nb) ? bsum[t] : 0;
    int x = v;
    #pragma unroll
    for (int off = 1; off < 64; off <<= 1) {
        int tt = __shfl_up(x, off);
        if (lane >= off) x += tt;
    }
    if (lane == 63) ws[w] = x;
    __syncthreads();
    int woff = 0;
    #pragma unroll
    for (int k = 0; k < 4; ++k) woff += (k < w) ? ws[k] : 0;
    int excl = x - v + woff;
    __syncthreads();
    if (t < nb) bsum[t] = excl;
    if (t == 255) *rp_end = excl + v;   // grand total = NEDGES
}

__global__ __launch_bounds__(256) void k_scan3(int* __restrict__ rp,
                                               const int* __restrict__ bsum,
                                               int* __restrict__ cursor, int n) {
    int i = blockIdx.x * 256 + threadIdx.x;
    if (i < n) {
        int r = rp[i] + bsum[i >> 8];
        rp[i] = r;
        cursor[i] = r;
    }
}

// partition-owned scatter, 16-bit: partition p = blockIdx&3 owns dst range
__global__ __launch_bounds__(256) void k_scatter_part16(
    const ushort* __restrict__ src16, const ushort* __restrict__ dst16,
    int* __restrict__ cursor, ushort* __restrict__ csr16, int n, int npp) {
    int part = blockIdx.x & (NPART - 1);
    int bip  = blockIdx.x >> 2;
    int nblk = gridDim.x >> 2;
    int lo = part * npp, hi = lo + npp;
    for (int i = bip * 256 + threadIdx.x; i < n; i += nblk * 256) {
        int d = dst16[i];
        if (d >= lo && d < hi) {
            int p = atomicAdd(&cursor[d], 1);
            csr16[p] = src16[i];
        }
    }
}

// ---------------------------------------------------------------------------
// weight transposes/converts
// ---------------------------------------------------------------------------
// W [K][128] f32 -> Wt [128][K] bf16
__global__ void k_wt(const float* __restrict__ W, __bf16* __restrict__ Wt, int K) {
    int i = blockIdx.x * blockDim.x + threadIdx.x;
    if (i >= K * 128) return;
    int k = i >> 7, c = i & 127;
    Wt[(size_t)c * K + k] = (__bf16)W[i];
}

// W3 [128][40] f32 -> Wt3 [48][128] bf16 (rows 40..47 zero)
__global__ void k_wt3(const float* __restrict__ W, __bf16* __restrict__ Wt) {
    int i = blockIdx.x * blockDim.x + threadIdx.x;
    if (i >= 48 * 128) return;
    int c = i >> 7, k = i & 127;
    Wt[(size_t)c * 128 + k] = (c < 40) ? (__bf16)W[(size_t)k * 40 + c] : (__bf16)0.f;
}

// ---------------------------------------------------------------------------
// MFMA bf16 GEMM, N=128, fused attention-score epilogue.
// AF32: A is fp32 (converted during LDS staging); else bf16.
// ---------------------------------------------------------------------------
template<bool AF32>
__global__ __launch_bounds__(256) void gemm_mfma_128(
    const void* __restrict__ Av, const __bf16* __restrict__ Wt,
    const float* __restrict__ al, const float* __restrict__ ar,
    __bf16* __restrict__ z, float* __restrict__ el, float* __restrict__ er,
    int M, int K)
{
    __shared__ alignas(16) __bf16 As[64 * 40];
    __shared__ alignas(16) __bf16 Bs[128 * 40];
    int tid = threadIdx.x;
    int wv = tid >> 6, l = tid & 63;
    int lr = l & 15, lk = l >> 4;
    int m0 = blockIdx.x * 64;
    f32x4 acc[8];
    f32x4 zero4 = {0.f, 0.f, 0.f, 0.f};
    #pragma unroll
    for (int nt = 0; nt < 8; ++nt) acc[nt] = zero4;

    int ar_ = tid >> 2, aq = tid & 3;
    for (int k0 = 0; k0 < K; k0 += 32) {
        {   // A tile: 64 x 32 bf16
            int m = m0 + ar_;
            if constexpr (AF32) {
                const float* A = (const float*)Av;
                __bf16 t8[8] = {};
                if (m < M) {
                    const float4* p = reinterpret_cast<const float4*>(&A[(size_t)m * K + k0 + aq * 8]);
                    float4 a = p[0], b = p[1];
                    t8[0] = (__bf16)a.x; t8[1] = (__bf16)a.y; t8[2] = (__bf16)a.z; t8[3] = (__bf16)a.w;
                    t8[4] = (__bf16)b.x; t8[5] = (__bf16)b.y; t8[6] = (__bf16)b.z; t8[7] = (__bf16)b.w;
                }
                *reinterpret_cast<uint4*>(&As[ar_ * 40 + aq * 8]) = *reinterpret_cast<uint4*>(t8);
            } else {
                const __bf16* A = (const __bf16*)Av;
                uint4 av = make_uint4(0, 0, 0, 0);
                if (m < M) av = *reinterpret_cast<const uint4*>(&A[(size_t)m * K + k0 + aq * 8]);
                *reinterpret_cast<uint4*>(&As[ar_ * 40 + aq * 8]) = av;
            }
        }
        {   // B tile: Wt rows (col-major W): 128 x 32 bf16
            #pragma unroll
            for (int t = 0; t < 2; ++t) {
                int cid = tid + t * 256;
                int c = cid >> 2, q = cid & 3;
                *reinterpret_cast<uint4*>(&Bs[c * 40 + q * 8]) =
                    *reinterpret_cast<const uint4*>(&Wt[(size_t)c * K + k0 + q * 8]);
            }
        }
        __syncthreads();
        bf16x8 af = *reinterpret_cast<const bf16x8*>(&As[(wv * 16 + lr) * 40 + lk * 8]);
        #pragma unroll
        for (int nt = 0; nt < 8; ++nt) {
            bf16x8 bfr = *reinterpret_cast<const bf16x8*>(&Bs[(nt * 16 + lr) * 40 + lk * 8]);
            acc[nt] = __builtin_amdgcn_mfma_f32_16x16x32_bf16(af, bfr, acc[nt], 0, 0, 0);
        }
        __syncthreads();
    }

    float alv[8], arv[8];
    #pragma unroll
    for (int nt = 0; nt < 8; ++nt) {
        alv[nt] = al[nt * 16 + lr];
        arv[nt] = ar[nt * 16 + lr];
    }
    #pragma unroll
    for (int r = 0; r < 4; ++r) {
        int m = m0 + wv * 16 + lk * 4 + r;   // C/D: row=(lane>>4)*4+reg, col=lane&15
        float pel[4], per_[4];
        #pragma unroll
        for (int h = 0; h < 4; ++h) {
            pel[h]  = acc[2 * h][r] * alv[2 * h] + acc[2 * h + 1][r] * alv[2 * h + 1];
            per_[h] = acc[2 * h][r] * arv[2 * h] + acc[2 * h + 1][r] * arv[2 * h + 1];
        }
        #pragma unroll
        for (int mk = 1; mk < 16; mk <<= 1) {
            #pragma unroll
            for (int h = 0; h < 4; ++h) {
                pel[h]  += __shfl_xor(pel[h], mk);
                per_[h] += __shfl_xor(per_[h], mk);
            }
        }
        if (m < M) {
            #pragma unroll
            for (int nt = 0; nt < 8; ++nt)
                z[(size_t)m * 128 + nt * 16 + lr] = (__bf16)acc[nt][r];
            if (lr == 0) {
                #pragma unroll
                for (int h = 0; h < 4; ++h) {
                    el[m * 4 + h] = pel[h];
                    er[m * 4 + h] = per_[h];
                }
            }
        }
    }
}

// ---------------------------------------------------------------------------
// layer-3 MFMA GEMM: z40[M,40(pad64)] = A[M,128] * W3[128,40], fused el3/er3.
// ---------------------------------------------------------------------------
__global__ __launch_bounds__(256) void gemm40_mfma(
    const __bf16* __restrict__ A, const __bf16* __restrict__ Wt3,
    const float* __restrict__ al, const float* __restrict__ arr,
    __bf16* __restrict__ z40, float* __restrict__ el3, float* __restrict__ er3,
    int M)
{
    __shared__ alignas(16) __bf16 As[64 * 40];
    __shared__ alignas(16) __bf16 Bs[48 * 40];
    int tid = threadIdx.x;
    int wv = tid >> 6, l = tid & 63;
    int lr = l & 15, lk = l >> 4;
    int m0 = blockIdx.x * 64;
    f32x4 acc[3];
    f32x4 zero4 = {0.f, 0.f, 0.f, 0.f};
    #pragma unroll
    for (int nt = 0; nt < 3; ++nt) acc[nt] = zero4;

    int ar_ = tid >> 2, aq = tid & 3;
    for (int k0 = 0; k0 < 128; k0 += 32) {
        {   // A tile: 64 x 32 bf16
            int m = m0 + ar_;
            uint4 av = make_uint4(0, 0, 0, 0);
            if (m < M) av = *reinterpret_cast<const uint4*>(&A[(size_t)m * 128 + k0 + aq * 8]);
            *reinterpret_cast<uint4*>(&As[ar_ * 40 + aq * 8]) = av;
        }
        if (tid < 192) {   // B tile: 48 x 32 bf16
            int c = tid >> 2, q = tid & 3;
            *reinterpret_cast<uint4*>(&Bs[c * 40 + q * 8]) =
                *reinterpret_cast<const uint4*>(&Wt3[(size_t)c * 128 + k0 + q * 8]);
        }
        __syncthreads();
        bf16x8 af = *reinterpret_cast<const bf16x8*>(&As[(wv * 16 + lr) * 40 + lk * 8]);
        #pragma unroll
        for (int nt = 0; nt < 3; ++nt) {
            bf16x8 bfr = *reinterpret_cast<const bf16x8*>(&Bs[(nt * 16 + lr) * 40 + lk * 8]);
            acc[nt] = __builtin_amdgcn_mfma_f32_16x16x32_bf16(af, bfr, acc[nt], 0, 0, 0);
        }
        __syncthreads();
    }

    float alv[3], arv[3];
    #pragma unroll
    for (int nt = 0; nt < 3; ++nt) {
        int col = nt * 16 + lr;
        alv[nt] = (col < 40) ? al[col] : 0.f;
        arv[nt] = (col < 40) ? arr[col] : 0.f;
    }
    #pragma unroll
    for (int r = 0; r < 4; ++r) {
        int m = m0 + wv * 16 + lk * 4 + r;
        float pel = acc[0][r] * alv[0] + acc[1][r] * alv[1] + acc[2][r] * alv[2];
        float per_ = acc[0][r] * arv[0] + acc[1][r] * arv[1] + acc[2][r] * arv[2];
        #pragma unroll
        for (int mk = 1; mk < 16; mk <<= 1) {
            pel  += __shfl_xor(pel, mk);
            per_ += __shfl_xor(per_, mk);
        }
        if (m < M) {
            #pragma unroll
            for (int nt = 0; nt < 3; ++nt) {
                int col = nt * 16 + lr;
                if (col < 40) z40[(size_t)m * 64 + col] = (__bf16)acc[nt][r];
            }
            if (lr == 0) { el3[m] = pel; er3[m] = per_; }
        }
    }
}

// ---------------------------------------------------------------------------
// edge-softmax + aggregation, layers 1-2 (H=4, F=32).
// ONE WAVE PER NODE: lane t: head g=t>>4, elems {g*32+2j,+1}; chunk=16 edges;
// full-chunk (16-deep) dword gather for max loads-in-flight.
// ---------------------------------------------------------------------------
__global__ __launch_bounds__(256) void gat_agg128w(
    const __bf16* __restrict__ z, const float* __restrict__ el,
    const float* __restrict__ er, const int* __restrict__ rp,
    const ushort* __restrict__ cs, const float* __restrict__ bias,
    __bf16* __restrict__ hout, int n_nodes)
{
    __shared__ uint2 sh[4][4][16];   // [wave][group][edge] = {row elem offset, p}
    int tid = threadIdx.x, w = tid >> 6, t = tid & 63;
    int g = t >> 4, j = t & 15;
    int nd = blockIdx.x * 4 + w;
    if (nd >= n_nodes) return;
    int beg = rp[nd], end = rp[nd + 1];
    float erv = er[nd * 4 + g];
    float m = -3.0e38f, s = 0.f, acc0 = 0.f, acc1 = 0.f;
    const int eoff = g * 32 + 2 * j;

    for (int c0 = beg; c0 < end; c0 += 16) {
        int ch = end - c0; if (ch > 16) ch = 16;
        // ---- phase 1: 16 edge scores per head group ----
        int sidx = (j < ch) ? (int)cs[c0 + j] : 0;
        float e = -3.0e38f;
        if (j < ch) {
            float ev = el[sidx * 4 + g] + erv;
            e = (ev > 0.f) ? ev : 0.2f * ev;
        }
        float cm = e;
        #pragma unroll
        for (int mk = 8; mk; mk >>= 1) cm = fmaxf(cm, __shfl_xor(cm, mk));
        float nm = fmaxf(m, cm);
        float p = (j < ch) ? __expf(e - nm) : 0.f;
        float ps = p;
        #pragma unroll
        for (int mk = 8; mk; mk >>= 1) ps += __shfl_xor(ps, mk);
        float so = __expf(m - nm);
        s = s * so + ps;
        acc0 *= so; acc1 *= so;
        m = nm;
        sh[w][g][j] = make_uint2((unsigned)(sidx << 7), __float_as_uint(p));
        // intra-wave LDS: each group reads only what it wrote -> no barrier
        // ---- phase 2: 16 dword gathers in flight (2 bf16 each) ----
        unsigned ld[16]; float pk[16];
        #pragma unroll
        for (int u = 0; u < 16; ++u) {
            uint2 v = sh[w][g][u];
            pk[u] = __uint_as_float(v.y);
            ld[u] = *reinterpret_cast<const unsigned*>(&z[(size_t)v.x + eoff]);
        }
        #pragma unroll
        for (int u = 0; u < 16; ++u) {
            float z0 = __uint_as_float(ld[u] << 16);
            float z1 = __uint_as_float(ld[u] & 0xffff0000u);
            acc0 += pk[u] * z0;
            acc1 += pk[u] * z1;
        }
    }
    float o0 = (end > beg) ? acc0 / s : 0.f;
    float o1 = (end > beg) ? acc1 / s : 0.f;
    o0 = fmaxf(o0 + bias[eoff], 0.f);       // relu (layers 1-2)
    o1 = fmaxf(o1 + bias[eoff + 1], 0.f);
    __bf16 t2[2] = {(__bf16)o0, (__bf16)o1};
    *reinterpret_cast<unsigned*>(&hout[(size_t)nd * 128 + eoff]) = *reinterpret_cast<unsigned*>(t2);
}

// ---------------------------------------------------------------------------
// layer-3 aggregation: chunk-parallel, 1 node per wave, + bias + log_softmax
// ---------------------------------------------------------------------------
__global__ __launch_bounds__(256) void gat_agg40c(
    const __bf16* __restrict__ z40, const float* __restrict__ el3,
    const float* __restrict__ er3, const int* __restrict__ rp,
    const ushort* __restrict__ cs, const float* __restrict__ bias,
    float* __restrict__ out, int n_nodes)
{
    __shared__ uint2 sh[4][64];
    int tid = threadIdx.x, wid = tid >> 6, lane = tid & 63;
    int nd = blockIdx.x * 4 + wid;
    if (nd >= n_nodes) return;
    bool act = lane < 40;
    int beg = rp[nd], end = rp[nd + 1];
    float erv = er3[nd];
    float m = -3.0e38f, s = 0.f, acc = 0.f;

    for (int c0 = beg; c0 < end; c0 += 64) {
        int ch = end - c0; if (ch > 64) ch = 64;
        int chp = (ch + 7) & ~7;
        int sidx = (lane < ch) ? (int)cs[c0 + lane] : 0;
        float e = -3.0e38f;
        if (lane < ch) {
            float ev = el3[sidx] + erv;
            e = (ev > 0.f) ? ev : 0.2f * ev;
        }
        float cm = e;
        #pragma unroll
        for (int mk = 32; mk; mk >>= 1) cm = fmaxf(cm, __shfl_xor(cm, mk));
        float nm = fmaxf(m, cm);
        float p = (lane < ch) ? __expf(e - nm) : 0.f;
        float ps = p;
        #pragma unroll
        for (int mk = 32; mk; mk >>= 1) ps += __shfl_xor(ps, mk);
        float so = __expf(m - nm);
        s = s * so + ps;
        acc *= so;
        m = nm;
        sh[wid][lane] = make_uint2((unsigned)(sidx << 6), __float_as_uint(p));
        for (int k = 0; k < chp; k += 8) {
            float zv[8], pk[8];
            #pragma unroll
            for (int u = 0; u < 8; ++u) {
                uint2 v = sh[wid][k + u];
                pk[u] = __uint_as_float(v.y);
                zv[u] = (float)z40[(size_t)v.x + lane];
            }
            #pragma unroll
            for (int u = 0; u < 8; ++u) acc += pk[u] * zv[u];
        }
    }
    float o = (end > beg) ? acc / s : 0.f;
    o += act ? bias[lane] : 0.f;
    float v = act ? o : -3.0e38f;
    float mx = v;
    #pragma unroll
    for (int off = 32; off > 0; off >>= 1) mx = fmaxf(mx, __shfl_xor(mx, off));
    float p2 = act ? __expf(o - mx) : 0.f;
    float sum = p2;
    #pragma unroll
    for (int off = 32; off > 0; off >>= 1) sum += __shfl_xor(sum, off);
    if (act) out[(size_t)nd * 40 + lane] = o - mx - __logf(sum);
}

// ---------------------------------------------------------------------------
extern "C" void kernel_launch(void* const* d_in, const int* in_sizes, int n_in,
                              void* d_out, int out_size, void* d_ws, size_t ws_size,
                              hipStream_t stream) {
    const float* features = (const float*)d_in[0];
    const int*   src      = (const int*)d_in[1];
    const int*   dst      = (const int*)d_in[2];
    const float* W1  = (const float*)d_in[3];
    const float* al1 = (const float*)d_in[4];
    const float* ar1 = (const float*)d_in[5];
    const float* b1  = (const float*)d_in[6];
    const float* W2  = (const float*)d_in[7];
    const float* al2 = (const float*)d_in[8];
    const float* ar2 = (const float*)d_in[9];
    const float* b2  = (const float*)d_in[10];
    const float* W3  = (const float*)d_in[11];
    const float* al3 = (const float*)d_in[12];
    const float* ar3 = (const float*)d_in[13];
    const float* b3  = (const float*)d_in[14];
    float* out = (float*)d_out;

    const int N = NNODES, E = NEDGES;
    const int NB = (N + 255) / 256;   // scan blocks = 196

    // workspace layout (bytes)
    char* ws = (char*)d_ws;
    __bf16* z40    = (__bf16*)(ws + 0);            // N*64*2 (layer 3)
    __bf16* Wt3    = (__bf16*)(ws + 6400000);      // 48*128*2
    __bf16* zb     = (__bf16*)(ws + 25600000);     // N*128*2
    __bf16* hb     = (__bf16*)(ws + 38400000);     // N*128*2
    float*  elb    = (float*)(ws + 51200000);      // N*4*4
    float*  erb    = (float*)(ws + 52000000);      // N*4*4
    __bf16* Wt1    = (__bf16*)(ws + 52800000);     // 128*256*2
    __bf16* Wt2    = (__bf16*)(ws + 52865536);     // 128*128*2
    int* row_ptr   = (int*)(ws + 52898304);        // (N+1)*4
    int* cursor    = (int*)(ws + 53098496);        // N*4
    int* bsum      = (int*)(ws + 53298496);        // 256*4
    ushort* src16  = (ushort*)(ws + 53299520);     // E*2
    ushort* dst16  = (ushort*)(ws + 54899520);     // E*2
    ushort* csr16  = (ushort*)(ws + 56499520);     // E*2 -> ends 58,099,520

    // ---- CSR build (16-bit) ----
    hipMemsetAsync(cursor, 0, (size_t)N * 4, stream);
    k_pack16<<<(E + 255) / 256, 256, 0, stream>>>(src, dst, src16, dst16, E);
    k_hist16<<<(E + 255) / 256, 256, 0, stream>>>(dst16, cursor, E);
    k_scan1<<<NB, 256, 0, stream>>>(cursor, row_ptr, bsum, N);
    k_scan2<<<1, 256, 0, stream>>>(bsum, &row_ptr[N], NB);
    k_scan3<<<NB, 256, 0, stream>>>(row_ptr, bsum, cursor, N);
    k_scatter_part16<<<2048, 256, 0, stream>>>(src16, dst16, cursor, csr16, E, N / NPART);

    // ---- weight converts ----
    k_wt<<<(256 * 128 + 255) / 256, 256, 0, stream>>>(W1, Wt1, 256);
    k_wt<<<(128 * 128 + 255) / 256, 256, 0, stream>>>(W2, Wt2, 128);
    k_wt3<<<(48 * 128 + 255) / 256, 256, 0, stream>>>(W3, Wt3);

    // ---- layer 1 (A = fp32 features, converted in staging) ----
    gemm_mfma_128<true><<<(N + 63) / 64, 256, 0, stream>>>(features, Wt1, al1, ar1, zb, elb, erb, N, 256);
    gat_agg128w<<<(N + 3) / 4, 256, 0, stream>>>(zb, elb, erb, row_ptr, csr16, b1, hb, N);

    // ---- layer 2 ----
    gemm_mfma_128<false><<<(N + 63) / 64, 256, 0, stream>>>(hb, Wt2, al2, ar2, zb, elb, erb, N, 128);
    gat_agg128w<<<(N + 3) / 4, 256, 0, stream>>>(zb, elb, erb, row_ptr, csr16, b2, hb, N);

    // ---- layer 3 ----
    gemm40_mfma<<<(N + 63) / 64, 256, 0, stream>>>(hb, Wt3, al3, ar3, z40, elb, erb, N);
    gat_agg40c<<<(N + 3) / 4, 256, 0, stream>>>(z40, elb, erb, row_ptr, csr16, b3, out, N);

    (void)in_sizes; (void)n_in; (void)out_size; (void)ws_size;
}

// Round 8
// 211.718 us; speedup vs baseline: 1.1603x; 1.1603x over previous
//
#include <hip/hip_runtime.h>
#include <hip/hip_bf16.h>
#include <math.h>

// Problem constants (GAT_66907000537778)
#define NNODES 50000
#define NEDGES 800000
#define FIN 256
#define HID 32
#define HEADS 4
#define OUTS 40
#define HIDDEN 128   // HEADS*HID

typedef __bf16 bf16x8 __attribute__((ext_vector_type(8)));
typedef float  f32x4  __attribute__((ext_vector_type(4)));

// ---------------------------------------------------------------------------
// CSR construction (grouped by dst), 16-bit indices (N < 65536).
// ONE atomic pass: hist returns each edge's within-node slot; scatter is then
// atomic-free (csr16[rp[d] + slot16[i]] = src16[i]).
// ---------------------------------------------------------------------------
__global__ void k_hist_slot(const int* __restrict__ src, const int* __restrict__ dst,
                            ushort* __restrict__ src16, ushort* __restrict__ dst16,
                            ushort* __restrict__ slot16, int* __restrict__ counts, int n) {
    int i = blockIdx.x * blockDim.x + threadIdx.x;
    if (i < n) {
        int s = src[i], d = dst[i];
        src16[i] = (ushort)s;
        dst16[i] = (ushort)d;
        slot16[i] = (ushort)atomicAdd(&counts[d], 1);
    }
}

__global__ __launch_bounds__(256) void k_scan1(const int* __restrict__ counts,
                                               int* __restrict__ pre,
                                               int* __restrict__ bsum, int n) {
    __shared__ int ws[4];
    int t = threadIdx.x, b = blockIdx.x, i = b * 256 + t;
    int lane = t & 63, w = t >> 6;
    int v = (i < n) ? counts[i] : 0;
    int x = v;
    #pragma unroll
    for (int off = 1; off < 64; off <<= 1) {
        int tt = __shfl_up(x, off);
        if (lane >= off) x += tt;
    }
    if (lane == 63) ws[w] = x;
    __syncthreads();
    int woff = 0;
    #pragma unroll
    for (int k = 0; k < 4; ++k) woff += (k < w) ? ws[k] : 0;
    int excl = x - v + woff;
    if (i < n) pre[i] = excl;
    if (t == 255) bsum[b] = excl + v;
}

__global__ __launch_bounds__(256) void k_scan2(int* __restrict__ bsum,
                                               int* __restrict__ rp_end, int nb) {
    __shared__ int ws[4];
    int t = threadIdx.x;
    int lane = t & 63, w = t >> 6;
    int v = (t < nb) ? bsum[t] : 0;
    int x = v;
    #pragma unroll
    for (int off = 1; off < 64; off <<= 1) {
        int tt = __shfl_up(x, off);
        if (lane >= off) x += tt;
    }
    if (lane == 63) ws[w] = x;
    __syncthreads();
    int woff = 0;
    #pragma unroll
    for (int k = 0; k < 4; ++k) woff += (k < w) ? ws[k] : 0;
    int excl = x - v + woff;
    __syncthreads();
    if (t < nb) bsum[t] = excl;
    if (t == 255) *rp_end = excl + v;   // grand total = NEDGES
}

__global__ __launch_bounds__(256) void k_scan3(int* __restrict__ rp,
                                               const int* __restrict__ bsum, int n) {
    int i = blockIdx.x * 256 + threadIdx.x;
    if (i < n) rp[i] += bsum[i >> 8];
}

// atomic-free scatter
__global__ __launch_bounds__(256) void k_scatter_ns(
    const ushort* __restrict__ src16, const ushort* __restrict__ dst16,
    const ushort* __restrict__ slot16, const int* __restrict__ rp,
    ushort* __restrict__ csr16, int n) {
    int i = blockIdx.x * blockDim.x + threadIdx.x;
    if (i < n) {
        int d = dst16[i];
        csr16[rp[d] + (int)slot16[i]] = src16[i];
    }
}

// ---------------------------------------------------------------------------
// weight transposes/converts
// ---------------------------------------------------------------------------
// W [K][128] f32 -> Wt [128][K] bf16
__global__ void k_wt(const float* __restrict__ W, __bf16* __restrict__ Wt, int K) {
    int i = blockIdx.x * blockDim.x + threadIdx.x;
    if (i >= K * 128) return;
    int k = i >> 7, c = i & 127;
    Wt[(size_t)c * K + k] = (__bf16)W[i];
}

// W3 [128][40] f32 -> Wt3 [48][128] bf16 (rows 40..47 zero)
__global__ void k_wt3(const float* __restrict__ W, __bf16* __restrict__ Wt) {
    int i = blockIdx.x * blockDim.x + threadIdx.x;
    if (i >= 48 * 128) return;
    int c = i >> 7, k = i & 127;
    Wt[(size_t)c * 128 + k] = (c < 40) ? (__bf16)W[(size_t)k * 40 + c] : (__bf16)0.f;
}

// ---------------------------------------------------------------------------
// MFMA bf16 GEMM, N=128, fused attention-score epilogue.
// AF32: A is fp32 (converted during LDS staging); else bf16.
// ---------------------------------------------------------------------------
template<bool AF32>
__global__ __launch_bounds__(256) void gemm_mfma_128(
    const void* __restrict__ Av, const __bf16* __restrict__ Wt,
    const float* __restrict__ al, const float* __restrict__ ar,
    __bf16* __restrict__ z, float* __restrict__ el, float* __restrict__ er,
    int M, int K)
{
    __shared__ alignas(16) __bf16 As[64 * 40];
    __shared__ alignas(16) __bf16 Bs[128 * 40];
    int tid = threadIdx.x;
    int wv = tid >> 6, l = tid & 63;
    int lr = l & 15, lk = l >> 4;
    int m0 = blockIdx.x * 64;
    f32x4 acc[8];
    f32x4 zero4 = {0.f, 0.f, 0.f, 0.f};
    #pragma unroll
    for (int nt = 0; nt < 8; ++nt) acc[nt] = zero4;

    int ar_ = tid >> 2, aq = tid & 3;
    for (int k0 = 0; k0 < K; k0 += 32) {
        {   // A tile: 64 x 32 bf16
            int m = m0 + ar_;
            if constexpr (AF32) {
                const float* A = (const float*)Av;
                __bf16 t8[8] = {};
                if (m < M) {
                    const float4* p = reinterpret_cast<const float4*>(&A[(size_t)m * K + k0 + aq * 8]);
                    float4 a = p[0], b = p[1];
                    t8[0] = (__bf16)a.x; t8[1] = (__bf16)a.y; t8[2] = (__bf16)a.z; t8[3] = (__bf16)a.w;
                    t8[4] = (__bf16)b.x; t8[5] = (__bf16)b.y; t8[6] = (__bf16)b.z; t8[7] = (__bf16)b.w;
                }
                *reinterpret_cast<uint4*>(&As[ar_ * 40 + aq * 8]) = *reinterpret_cast<uint4*>(t8);
            } else {
                const __bf16* A = (const __bf16*)Av;
                uint4 av = make_uint4(0, 0, 0, 0);
                if (m < M) av = *reinterpret_cast<const uint4*>(&A[(size_t)m * K + k0 + aq * 8]);
                *reinterpret_cast<uint4*>(&As[ar_ * 40 + aq * 8]) = av;
            }
        }
        {   // B tile: Wt rows (col-major W): 128 x 32 bf16
            #pragma unroll
            for (int t = 0; t < 2; ++t) {
                int cid = tid + t * 256;
                int c = cid >> 2, q = cid & 3;
                *reinterpret_cast<uint4*>(&Bs[c * 40 + q * 8]) =
                    *reinterpret_cast<const uint4*>(&Wt[(size_t)c * K + k0 + q * 8]);
            }
        }
        __syncthreads();
        bf16x8 af = *reinterpret_cast<const bf16x8*>(&As[(wv * 16 + lr) * 40 + lk * 8]);
        #pragma unroll
        for (int nt = 0; nt < 8; ++nt) {
            bf16x8 bfr = *reinterpret_cast<const bf16x8*>(&Bs[(nt * 16 + lr) * 40 + lk * 8]);
            acc[nt] = __builtin_amdgcn_mfma_f32_16x16x32_bf16(af, bfr, acc[nt], 0, 0, 0);
        }
        __syncthreads();
    }

    float alv[8], arv[8];
    #pragma unroll
    for (int nt = 0; nt < 8; ++nt) {
        alv[nt] = al[nt * 16 + lr];
        arv[nt] = ar[nt * 16 + lr];
    }
    #pragma unroll
    for (int r = 0; r < 4; ++r) {
        int m = m0 + wv * 16 + lk * 4 + r;   // C/D: row=(lane>>4)*4+reg, col=lane&15
        float pel[4], per_[4];
        #pragma unroll
        for (int h = 0; h < 4; ++h) {
            pel[h]  = acc[2 * h][r] * alv[2 * h] + acc[2 * h + 1][r] * alv[2 * h + 1];
            per_[h] = acc[2 * h][r] * arv[2 * h] + acc[2 * h + 1][r] * arv[2 * h + 1];
        }
        #pragma unroll
        for (int mk = 1; mk < 16; mk <<= 1) {
            #pragma unroll
            for (int h = 0; h < 4; ++h) {
                pel[h]  += __shfl_xor(pel[h], mk);
                per_[h] += __shfl_xor(per_[h], mk);
            }
        }
        if (m < M) {
            #pragma unroll
            for (int nt = 0; nt < 8; ++nt)
                z[(size_t)m * 128 + nt * 16 + lr] = (__bf16)acc[nt][r];
            if (lr == 0) {
                #pragma unroll
                for (int h = 0; h < 4; ++h) {
                    el[m * 4 + h] = pel[h];
                    er[m * 4 + h] = per_[h];
                }
            }
        }
    }
}

// ---------------------------------------------------------------------------
// layer-3 MFMA GEMM: z40[M,40(pad64)] = A[M,128] * W3[128,40], fused el3/er3.
// ---------------------------------------------------------------------------
__global__ __launch_bounds__(256) void gemm40_mfma(
    const __bf16* __restrict__ A, const __bf16* __restrict__ Wt3,
    const float* __restrict__ al, const float* __restrict__ arr,
    __bf16* __restrict__ z40, float* __restrict__ el3, float* __restrict__ er3,
    int M)
{
    __shared__ alignas(16) __bf16 As[64 * 40];
    __shared__ alignas(16) __bf16 Bs[48 * 40];
    int tid = threadIdx.x;
    int wv = tid >> 6, l = tid & 63;
    int lr = l & 15, lk = l >> 4;
    int m0 = blockIdx.x * 64;
    f32x4 acc[3];
    f32x4 zero4 = {0.f, 0.f, 0.f, 0.f};
    #pragma unroll
    for (int nt = 0; nt < 3; ++nt) acc[nt] = zero4;

    int ar_ = tid >> 2, aq = tid & 3;
    for (int k0 = 0; k0 < 128; k0 += 32) {
        {   // A tile: 64 x 32 bf16
            int m = m0 + ar_;
            uint4 av = make_uint4(0, 0, 0, 0);
            if (m < M) av = *reinterpret_cast<const uint4*>(&A[(size_t)m * 128 + k0 + aq * 8]);
            *reinterpret_cast<uint4*>(&As[ar_ * 40 + aq * 8]) = av;
        }
        if (tid < 192) {   // B tile: 48 x 32 bf16
            int c = tid >> 2, q = tid & 3;
            *reinterpret_cast<uint4*>(&Bs[c * 40 + q * 8]) =
                *reinterpret_cast<const uint4*>(&Wt3[(size_t)c * 128 + k0 + q * 8]);
        }
        __syncthreads();
        bf16x8 af = *reinterpret_cast<const bf16x8*>(&As[(wv * 16 + lr) * 40 + lk * 8]);
        #pragma unroll
        for (int nt = 0; nt < 3; ++nt) {
            bf16x8 bfr = *reinterpret_cast<const bf16x8*>(&Bs[(nt * 16 + lr) * 40 + lk * 8]);
            acc[nt] = __builtin_amdgcn_mfma_f32_16x16x32_bf16(af, bfr, acc[nt], 0, 0, 0);
        }
        __syncthreads();
    }

    float alv[3], arv[3];
    #pragma unroll
    for (int nt = 0; nt < 3; ++nt) {
        int col = nt * 16 + lr;
        alv[nt] = (col < 40) ? al[col] : 0.f;
        arv[nt] = (col < 40) ? arr[col] : 0.f;
    }
    #pragma unroll
    for (int r = 0; r < 4; ++r) {
        int m = m0 + wv * 16 + lk * 4 + r;
        float pel = acc[0][r] * alv[0] + acc[1][r] * alv[1] + acc[2][r] * alv[2];
        float per_ = acc[0][r] * arv[0] + acc[1][r] * arv[1] + acc[2][r] * arv[2];
        #pragma unroll
        for (int mk = 1; mk < 16; mk <<= 1) {
            pel  += __shfl_xor(pel, mk);
            per_ += __shfl_xor(per_, mk);
        }
        if (m < M) {
            #pragma unroll
            for (int nt = 0; nt < 3; ++nt) {
                int col = nt * 16 + lr;
                if (col < 40) z40[(size_t)m * 64 + col] = (__bf16)acc[nt][r];
            }
            if (lr == 0) { el3[m] = pel; er3[m] = per_; }
        }
    }
}

// ---------------------------------------------------------------------------
// edge-softmax + aggregation, layers 1-2 (H=4, F=32).
// ONE WAVE PER NODE: lane t: head g=t>>4, elems {g*32+2j,+1}; chunk=16 edges;
// 8-deep dword gathers (round-6 measured shape).
// ---------------------------------------------------------------------------
__global__ __launch_bounds__(256) void gat_agg128w(
    const __bf16* __restrict__ z, const float* __restrict__ el,
    const float* __restrict__ er, const int* __restrict__ rp,
    const ushort* __restrict__ cs, const float* __restrict__ bias,
    __bf16* __restrict__ hout, int n_nodes)
{
    __shared__ uint2 sh[4][4][16];   // [wave][group][edge] = {row elem offset, p}
    int tid = threadIdx.x, w = tid >> 6, t = tid & 63;
    int g = t >> 4, j = t & 15;
    int nd = blockIdx.x * 4 + w;
    if (nd >= n_nodes) return;
    int beg = rp[nd], end = rp[nd + 1];
    float erv = er[nd * 4 + g];
    float m = -3.0e38f, s = 0.f, acc0 = 0.f, acc1 = 0.f;
    const int eoff = g * 32 + 2 * j;

    for (int c0 = beg; c0 < end; c0 += 16) {
        int ch = end - c0; if (ch > 16) ch = 16;
        int chp = (ch + 7) & ~7;
        // ---- phase 1: 16 edge scores per head group ----
        int sidx = (j < ch) ? (int)cs[c0 + j] : 0;
        float e = -3.0e38f;
        if (j < ch) {
            float ev = el[sidx * 4 + g] + erv;
            e = (ev > 0.f) ? ev : 0.2f * ev;
        }
        float cm = e;
        #pragma unroll
        for (int mk = 8; mk; mk >>= 1) cm = fmaxf(cm, __shfl_xor(cm, mk));
        float nm = fmaxf(m, cm);
        float p = (j < ch) ? __expf(e - nm) : 0.f;
        float ps = p;
        #pragma unroll
        for (int mk = 8; mk; mk >>= 1) ps += __shfl_xor(ps, mk);
        float so = __expf(m - nm);
        s = s * so + ps;
        acc0 *= so; acc1 *= so;
        m = nm;
        sh[w][g][j] = make_uint2((unsigned)(sidx << 7), __float_as_uint(p));
        // intra-wave LDS: each group reads only what it wrote -> no barrier
        // ---- phase 2: 8-deep dword gathers (2 bf16 each) ----
        for (int k = 0; k < chp; k += 8) {
            unsigned ld[8]; float pk[8];
            #pragma unroll
            for (int u = 0; u < 8; ++u) {
                uint2 v = sh[w][g][k + u];
                pk[u] = __uint_as_float(v.y);
                ld[u] = *reinterpret_cast<const unsigned*>(&z[(size_t)v.x + eoff]);
            }
            #pragma unroll
            for (int u = 0; u < 8; ++u) {
                float z0 = __uint_as_float(ld[u] << 16);
                float z1 = __uint_as_float(ld[u] & 0xffff0000u);
                acc0 += pk[u] * z0;
                acc1 += pk[u] * z1;
            }
        }
    }
    float o0 = (end > beg) ? acc0 / s : 0.f;
    float o1 = (end > beg) ? acc1 / s : 0.f;
    o0 = fmaxf(o0 + bias[eoff], 0.f);       // relu (layers 1-2)
    o1 = fmaxf(o1 + bias[eoff + 1], 0.f);
    __bf16 t2[2] = {(__bf16)o0, (__bf16)o1};
    *reinterpret_cast<unsigned*>(&hout[(size_t)nd * 128 + eoff]) = *reinterpret_cast<unsigned*>(t2);
}

// ---------------------------------------------------------------------------
// layer-3 aggregation: chunk-parallel, 1 node per wave, + bias + log_softmax
// ---------------------------------------------------------------------------
__global__ __launch_bounds__(256) void gat_agg40c(
    const __bf16* __restrict__ z40, const float* __restrict__ el3,
    const float* __restrict__ er3, const int* __restrict__ rp,
    const ushort* __restrict__ cs, const float* __restrict__ bias,
    float* __restrict__ out, int n_nodes)
{
    __shared__ uint2 sh[4][64];
    int tid = threadIdx.x, wid = tid >> 6, lane = tid & 63;
    int nd = blockIdx.x * 4 + wid;
    if (nd >= n_nodes) return;
    bool act = lane < 40;
    int beg = rp[nd], end = rp[nd + 1];
    float erv = er3[nd];
    float m = -3.0e38f, s = 0.f, acc = 0.f;

    for (int c0 = beg; c0 < end; c0 += 64) {
        int ch = end - c0; if (ch > 64) ch = 64;
        int chp = (ch + 7) & ~7;
        int sidx = (lane < ch) ? (int)cs[c0 + lane] : 0;
        float e = -3.0e38f;
        if (lane < ch) {
            float ev = el3[sidx] + erv;
            e = (ev > 0.f) ? ev : 0.2f * ev;
        }
        float cm = e;
        #pragma unroll
        for (int mk = 32; mk; mk >>= 1) cm = fmaxf(cm, __shfl_xor(cm, mk));
        float nm = fmaxf(m, cm);
        float p = (lane < ch) ? __expf(e - nm) : 0.f;
        float ps = p;
        #pragma unroll
        for (int mk = 32; mk; mk >>= 1) ps += __shfl_xor(ps, mk);
        float so = __expf(m - nm);
        s = s * so + ps;
        acc *= so;
        m = nm;
        sh[wid][lane] = make_uint2((unsigned)(sidx << 6), __float_as_uint(p));
        for (int k = 0; k < chp; k += 8) {
            float zv[8], pk[8];
            #pragma unroll
            for (int u = 0; u < 8; ++u) {
                uint2 v = sh[wid][k + u];
                pk[u] = __uint_as_float(v.y);
                zv[u] = (float)z40[(size_t)v.x + lane];
            }
            #pragma unroll
            for (int u = 0; u < 8; ++u) acc += pk[u] * zv[u];
        }
    }
    float o = (end > beg) ? acc / s : 0.f;
    o += act ? bias[lane] : 0.f;
    float v = act ? o : -3.0e38f;
    float mx = v;
    #pragma unroll
    for (int off = 32; off > 0; off >>= 1) mx = fmaxf(mx, __shfl_xor(mx, off));
    float p2 = act ? __expf(o - mx) : 0.f;
    float sum = p2;
    #pragma unroll
    for (int off = 32; off > 0; off >>= 1) sum += __shfl_xor(sum, off);
    if (act) out[(size_t)nd * 40 + lane] = o - mx - __logf(sum);
}

// ---------------------------------------------------------------------------
extern "C" void kernel_launch(void* const* d_in, const int* in_sizes, int n_in,
                              void* d_out, int out_size, void* d_ws, size_t ws_size,
                              hipStream_t stream) {
    const float* features = (const float*)d_in[0];
    const int*   src      = (const int*)d_in[1];
    const int*   dst      = (const int*)d_in[2];
    const float* W1  = (const float*)d_in[3];
    const float* al1 = (const float*)d_in[4];
    const float* ar1 = (const float*)d_in[5];
    const float* b1  = (const float*)d_in[6];
    const float* W2  = (const float*)d_in[7];
    const float* al2 = (const float*)d_in[8];
    const float* ar2 = (const float*)d_in[9];
    const float* b2  = (const float*)d_in[10];
    const float* W3  = (const float*)d_in[11];
    const float* al3 = (const float*)d_in[12];
    const float* ar3 = (const float*)d_in[13];
    const float* b3  = (const float*)d_in[14];
    float* out = (float*)d_out;

    const int N = NNODES, E = NEDGES;
    const int NB = (N + 255) / 256;   // scan blocks = 196

    // workspace layout (bytes)
    char* ws = (char*)d_ws;
    __bf16* z40    = (__bf16*)(ws + 0);            // N*64*2 (layer 3)
    __bf16* Wt3    = (__bf16*)(ws + 6400000);      // 48*128*2
    ushort* slot16 = (ushort*)(ws + 8000000);      // E*2 (CSR build only)
    __bf16* zb     = (__bf16*)(ws + 25600000);     // N*128*2
    __bf16* hb     = (__bf16*)(ws + 38400000);     // N*128*2
    float*  elb    = (float*)(ws + 51200000);      // N*4*4
    float*  erb    = (float*)(ws + 52000000);      // N*4*4
    __bf16* Wt1    = (__bf16*)(ws + 52800000);     // 128*256*2
    __bf16* Wt2    = (__bf16*)(ws + 52865536);     // 128*128*2
    int* row_ptr   = (int*)(ws + 52898304);        // (N+1)*4
    int* cursor    = (int*)(ws + 53098496);        // N*4 (hist counts)
    int* bsum      = (int*)(ws + 53298496);        // 256*4
    ushort* src16  = (ushort*)(ws + 53299520);     // E*2
    ushort* dst16  = (ushort*)(ws + 54899520);     // E*2
    ushort* csr16  = (ushort*)(ws + 56499520);     // E*2 -> ends 58,099,520

    // ---- CSR build: single atomic pass ----
    hipMemsetAsync(cursor, 0, (size_t)N * 4, stream);
    k_hist_slot<<<(E + 255) / 256, 256, 0, stream>>>(src, dst, src16, dst16, slot16, cursor, E);
    k_scan1<<<NB, 256, 0, stream>>>(cursor, row_ptr, bsum, N);
    k_scan2<<<1, 256, 0, stream>>>(bsum, &row_ptr[N], NB);
    k_scan3<<<NB, 256, 0, stream>>>(row_ptr, bsum, N);
    k_scatter_ns<<<(E + 255) / 256, 256, 0, stream>>>(src16, dst16, slot16, row_ptr, csr16, E);

    // ---- weight converts ----
    k_wt<<<(256 * 128 + 255) / 256, 256, 0, stream>>>(W1, Wt1, 256);
    k_wt<<<(128 * 128 + 255) / 256, 256, 0, stream>>>(W2, Wt2, 128);
    k_wt3<<<(48 * 128 + 255) / 256, 256, 0, stream>>>(W3, Wt3);

    // ---- layer 1 (A = fp32 features, converted in staging) ----
    gemm_mfma_128<true><<<(N + 63) / 64, 256, 0, stream>>>(features, Wt1, al1, ar1, zb, elb, erb, N, 256);
    gat_agg128w<<<(N + 3) / 4, 256, 0, stream>>>(zb, elb, erb, row_ptr, csr16, b1, hb, N);

    // ---- layer 2 ----
    gemm_mfma_128<false><<<(N + 63) / 64, 256, 0, stream>>>(hb, Wt2, al2, ar2, zb, elb, erb, N, 128);
    gat_agg128w<<<(N + 3) / 4, 256, 0, stream>>>(zb, elb, erb, row_ptr, csr16, b2, hb, N);

    // ---- layer 3 ----
    gemm40_mfma<<<(N + 63) / 64, 256, 0, stream>>>(hb, Wt3, al3, ar3, z40, elb, erb, N);
    gat_agg40c<<<(N + 3) / 4, 256, 0, stream>>>(z40, elb, erb, row_ptr, csr16, b3, out, N);

    (void)in_sizes; (void)n_in; (void)out_size; (void)ws_size;
}

// Round 9
// 204.741 us; speedup vs baseline: 1.1999x; 1.0341x over previous
//
#include <hip/hip_runtime.h>
#include <hip/hip_bf16.h>
#include <math.h>

// Problem constants (GAT_66907000537778)
#define NNODES 50000
#define NEDGES 800000
#define FIN 256
#define HID 32
#define HEADS 4
#define OUTS 40
#define HIDDEN 128   // HEADS*HID
#define NGB 782      // gemm blocks for M=50000, tile 64
#define NHB 1024     // hist blocks (grid-stride) in fused kernel

typedef __bf16 bf16x8 __attribute__((ext_vector_type(8)));
typedef float  f32x4  __attribute__((ext_vector_type(4)));

// ---------------------------------------------------------------------------
// prep: all weight converts + cursor zero in ONE launch (412 blocks)
// ---------------------------------------------------------------------------
__global__ __launch_bounds__(256) void k_prep(
    const float* __restrict__ W1, const float* __restrict__ W2,
    const float* __restrict__ W3, __bf16* __restrict__ Wt1,
    __bf16* __restrict__ Wt2, __bf16* __restrict__ Wt3, int* __restrict__ cursor) {
    int b = blockIdx.x, t = threadIdx.x;
    if (b < 128) {                 // W1 [256][128] -> Wt1 [128][256]
        int i = b * 256 + t;
        int k = i >> 7, c = i & 127;
        Wt1[(size_t)c * 256 + k] = (__bf16)W1[i];
    } else if (b < 192) {          // W2 [128][128] -> Wt2 [128][128]
        int i = (b - 128) * 256 + t;
        int k = i >> 7, c = i & 127;
        Wt2[(size_t)c * 128 + k] = (__bf16)W2[i];
    } else if (b < 216) {          // W3 [128][40] -> Wt3 [48][128], rows 40..47 zero
        int i = (b - 192) * 256 + t;
        int c = i >> 7, k = i & 127;
        Wt3[(size_t)c * 128 + k] = (c < 40) ? (__bf16)W3[(size_t)k * 40 + c] : (__bf16)0.f;
    } else {                       // zero hist counts
        int i = (b - 216) * 256 + t;
        if (i < NNODES) cursor[i] = 0;
    }
}

// ---------------------------------------------------------------------------
// device bodies for the fused kernel
// ---------------------------------------------------------------------------
__device__ __forceinline__ void dev_hist_slot(
    int bid, const int* __restrict__ src, const int* __restrict__ dst,
    ushort* __restrict__ src16, ushort* __restrict__ dst16,
    ushort* __restrict__ slot16, int* __restrict__ counts, int n) {
    for (int i = bid * 256 + threadIdx.x; i < n; i += NHB * 256) {
        int s = src[i], d = dst[i];
        src16[i] = (ushort)s;
        dst16[i] = (ushort)d;
        slot16[i] = (ushort)atomicAdd(&counts[d], 1);
    }
}

__device__ __forceinline__ void dev_gemm128_f32(
    int bid, const float* __restrict__ A, const __bf16* __restrict__ Wt,
    const float* __restrict__ al, const float* __restrict__ ar,
    __bf16* __restrict__ z, float* __restrict__ el, float* __restrict__ er,
    int M, int K)
{
    __shared__ alignas(16) __bf16 As[64 * 40];
    __shared__ alignas(16) __bf16 Bs[128 * 40];
    int tid = threadIdx.x;
    int wv = tid >> 6, l = tid & 63;
    int lr = l & 15, lk = l >> 4;
    int m0 = bid * 64;
    f32x4 acc[8];
    f32x4 zero4 = {0.f, 0.f, 0.f, 0.f};
    #pragma unroll
    for (int nt = 0; nt < 8; ++nt) acc[nt] = zero4;

    int ar_ = tid >> 2, aq = tid & 3;
    for (int k0 = 0; k0 < K; k0 += 32) {
        {   // A tile: 64 x 32, f32 -> bf16 in staging
            int m = m0 + ar_;
            __bf16 t8[8] = {};
            if (m < M) {
                const float4* p = reinterpret_cast<const float4*>(&A[(size_t)m * K + k0 + aq * 8]);
                float4 a = p[0], b = p[1];
                t8[0] = (__bf16)a.x; t8[1] = (__bf16)a.y; t8[2] = (__bf16)a.z; t8[3] = (__bf16)a.w;
                t8[4] = (__bf16)b.x; t8[5] = (__bf16)b.y; t8[6] = (__bf16)b.z; t8[7] = (__bf16)b.w;
            }
            *reinterpret_cast<uint4*>(&As[ar_ * 40 + aq * 8]) = *reinterpret_cast<uint4*>(t8);
        }
        {   // B tile: 128 x 32
            #pragma unroll
            for (int t = 0; t < 2; ++t) {
                int cid = tid + t * 256;
                int c = cid >> 2, q = cid & 3;
                *reinterpret_cast<uint4*>(&Bs[c * 40 + q * 8]) =
                    *reinterpret_cast<const uint4*>(&Wt[(size_t)c * K + k0 + q * 8]);
            }
        }
        __syncthreads();
        bf16x8 af = *reinterpret_cast<const bf16x8*>(&As[(wv * 16 + lr) * 40 + lk * 8]);
        #pragma unroll
        for (int nt = 0; nt < 8; ++nt) {
            bf16x8 bfr = *reinterpret_cast<const bf16x8*>(&Bs[(nt * 16 + lr) * 40 + lk * 8]);
            acc[nt] = __builtin_amdgcn_mfma_f32_16x16x32_bf16(af, bfr, acc[nt], 0, 0, 0);
        }
        __syncthreads();
    }

    float alv[8], arv[8];
    #pragma unroll
    for (int nt = 0; nt < 8; ++nt) {
        alv[nt] = al[nt * 16 + lr];
        arv[nt] = ar[nt * 16 + lr];
    }
    #pragma unroll
    for (int r = 0; r < 4; ++r) {
        int m = m0 + wv * 16 + lk * 4 + r;   // C/D: row=(lane>>4)*4+reg, col=lane&15
        float pel[4], per_[4];
        #pragma unroll
        for (int h = 0; h < 4; ++h) {
            pel[h]  = acc[2 * h][r] * alv[2 * h] + acc[2 * h + 1][r] * alv[2 * h + 1];
            per_[h] = acc[2 * h][r] * arv[2 * h] + acc[2 * h + 1][r] * arv[2 * h + 1];
        }
        #pragma unroll
        for (int mk = 1; mk < 16; mk <<= 1) {
            #pragma unroll
            for (int h = 0; h < 4; ++h) {
                pel[h]  += __shfl_xor(pel[h], mk);
                per_[h] += __shfl_xor(per_[h], mk);
            }
        }
        if (m < M) {
            #pragma unroll
            for (int nt = 0; nt < 8; ++nt)
                z[(size_t)m * 128 + nt * 16 + lr] = (__bf16)acc[nt][r];
            if (lr == 0) {
                #pragma unroll
                for (int h = 0; h < 4; ++h) {
                    el[m * 4 + h] = pel[h];
                    er[m * 4 + h] = per_[h];
                }
            }
        }
    }
}

// fused: layer-1 GEMM (blocks < NGB) + hist_slot (blocks >= NGB).
// Independent work; atomic-wait waves of hist hide under GEMM compute.
__global__ __launch_bounds__(256) void k_fused_g1h(
    const float* __restrict__ features, const __bf16* __restrict__ Wt1,
    const float* __restrict__ al1, const float* __restrict__ ar1,
    __bf16* __restrict__ zb, float* __restrict__ elb, float* __restrict__ erb,
    const int* __restrict__ src, const int* __restrict__ dst,
    ushort* __restrict__ src16, ushort* __restrict__ dst16,
    ushort* __restrict__ slot16, int* __restrict__ counts)
{
    int b = blockIdx.x;
    if (b < NGB) {
        dev_gemm128_f32(b, features, Wt1, al1, ar1, zb, elb, erb, NNODES, FIN);
    } else {
        dev_hist_slot(b - NGB, src, dst, src16, dst16, slot16, counts, NEDGES);
    }
}

// ---------------------------------------------------------------------------
// scans (row_ptr from counts)
// ---------------------------------------------------------------------------
__global__ __launch_bounds__(256) void k_scan1(const int* __restrict__ counts,
                                               int* __restrict__ pre,
                                               int* __restrict__ bsum, int n) {
    __shared__ int ws[4];
    int t = threadIdx.x, b = blockIdx.x, i = b * 256 + t;
    int lane = t & 63, w = t >> 6;
    int v = (i < n) ? counts[i] : 0;
    int x = v;
    #pragma unroll
    for (int off = 1; off < 64; off <<= 1) {
        int tt = __shfl_up(x, off);
        if (lane >= off) x += tt;
    }
    if (lane == 63) ws[w] = x;
    __syncthreads();
    int woff = 0;
    #pragma unroll
    for (int k = 0; k < 4; ++k) woff += (k < w) ? ws[k] : 0;
    int excl = x - v + woff;
    if (i < n) pre[i] = excl;
    if (t == 255) bsum[b] = excl + v;
}

__global__ __launch_bounds__(256) void k_scan2(int* __restrict__ bsum,
                                               int* __restrict__ rp_end, int nb) {
    __shared__ int ws[4];
    int t = threadIdx.x;
    int lane = t & 63, w = t >> 6;
    int v = (t < nb) ? bsum[t] : 0;
    int x = v;
    #pragma unroll
    for (int off = 1; off < 64; off <<= 1) {
        int tt = __shfl_up(x, off);
        if (lane >= off) x += tt;
    }
    if (lane == 63) ws[w] = x;
    __syncthreads();
    int woff = 0;
    #pragma unroll
    for (int k = 0; k < 4; ++k) woff += (k < w) ? ws[k] : 0;
    int excl = x - v + woff;
    __syncthreads();
    if (t < nb) bsum[t] = excl;
    if (t == 255) *rp_end = excl + v;   // grand total = NEDGES
}

__global__ __launch_bounds__(256) void k_scan3(int* __restrict__ rp,
                                               const int* __restrict__ bsum, int n) {
    int i = blockIdx.x * 256 + threadIdx.x;
    if (i < n) rp[i] += bsum[i >> 8];
}

// atomic-free scatter
__global__ __launch_bounds__(256) void k_scatter_ns(
    const ushort* __restrict__ src16, const ushort* __restrict__ dst16,
    const ushort* __restrict__ slot16, const int* __restrict__ rp,
    ushort* __restrict__ csr16, int n) {
    int i = blockIdx.x * blockDim.x + threadIdx.x;
    if (i < n) {
        int d = dst16[i];
        csr16[rp[d] + (int)slot16[i]] = src16[i];
    }
}

// ---------------------------------------------------------------------------
// standalone MFMA GEMM (layer 2, bf16 input), fused attention epilogue
// ---------------------------------------------------------------------------
__global__ __launch_bounds__(256) void gemm_mfma_128b(
    const __bf16* __restrict__ A, const __bf16* __restrict__ Wt,
    const float* __restrict__ al, const float* __restrict__ ar,
    __bf16* __restrict__ z, float* __restrict__ el, float* __restrict__ er,
    int M, int K)
{
    __shared__ alignas(16) __bf16 As[64 * 40];
    __shared__ alignas(16) __bf16 Bs[128 * 40];
    int tid = threadIdx.x;
    int wv = tid >> 6, l = tid & 63;
    int lr = l & 15, lk = l >> 4;
    int m0 = blockIdx.x * 64;
    f32x4 acc[8];
    f32x4 zero4 = {0.f, 0.f, 0.f, 0.f};
    #pragma unroll
    for (int nt = 0; nt < 8; ++nt) acc[nt] = zero4;

    int ar_ = tid >> 2, aq = tid & 3;
    for (int k0 = 0; k0 < K; k0 += 32) {
        {
            int m = m0 + ar_;
            uint4 av = make_uint4(0, 0, 0, 0);
            if (m < M) av = *reinterpret_cast<const uint4*>(&A[(size_t)m * K + k0 + aq * 8]);
            *reinterpret_cast<uint4*>(&As[ar_ * 40 + aq * 8]) = av;
        }
        {
            #pragma unroll
            for (int t = 0; t < 2; ++t) {
                int cid = tid + t * 256;
                int c = cid >> 2, q = cid & 3;
                *reinterpret_cast<uint4*>(&Bs[c * 40 + q * 8]) =
                    *reinterpret_cast<const uint4*>(&Wt[(size_t)c * K + k0 + q * 8]);
            }
        }
        __syncthreads();
        bf16x8 af = *reinterpret_cast<const bf16x8*>(&As[(wv * 16 + lr) * 40 + lk * 8]);
        #pragma unroll
        for (int nt = 0; nt < 8; ++nt) {
            bf16x8 bfr = *reinterpret_cast<const bf16x8*>(&Bs[(nt * 16 + lr) * 40 + lk * 8]);
            acc[nt] = __builtin_amdgcn_mfma_f32_16x16x32_bf16(af, bfr, acc[nt], 0, 0, 0);
        }
        __syncthreads();
    }

    float alv[8], arv[8];
    #pragma unroll
    for (int nt = 0; nt < 8; ++nt) {
        alv[nt] = al[nt * 16 + lr];
        arv[nt] = ar[nt * 16 + lr];
    }
    #pragma unroll
    for (int r = 0; r < 4; ++r) {
        int m = m0 + wv * 16 + lk * 4 + r;
        float pel[4], per_[4];
        #pragma unroll
        for (int h = 0; h < 4; ++h) {
            pel[h]  = acc[2 * h][r] * alv[2 * h] + acc[2 * h + 1][r] * alv[2 * h + 1];
            per_[h] = acc[2 * h][r] * arv[2 * h] + acc[2 * h + 1][r] * arv[2 * h + 1];
        }
        #pragma unroll
        for (int mk = 1; mk < 16; mk <<= 1) {
            #pragma unroll
            for (int h = 0; h < 4; ++h) {
                pel[h]  += __shfl_xor(pel[h], mk);
                per_[h] += __shfl_xor(per_[h], mk);
            }
        }
        if (m < M) {
            #pragma unroll
            for (int nt = 0; nt < 8; ++nt)
                z[(size_t)m * 128 + nt * 16 + lr] = (__bf16)acc[nt][r];
            if (lr == 0) {
                #pragma unroll
                for (int h = 0; h < 4; ++h) {
                    el[m * 4 + h] = pel[h];
                    er[m * 4 + h] = per_[h];
                }
            }
        }
    }
}

// ---------------------------------------------------------------------------
// layer-3 MFMA GEMM: z40[M,40(pad64)] = A[M,128] * W3[128,40], fused el3/er3.
// ---------------------------------------------------------------------------
__global__ __launch_bounds__(256) void gemm40_mfma(
    const __bf16* __restrict__ A, const __bf16* __restrict__ Wt3,
    const float* __restrict__ al, const float* __restrict__ arr,
    __bf16* __restrict__ z40, float* __restrict__ el3, float* __restrict__ er3,
    int M)
{
    __shared__ alignas(16) __bf16 As[64 * 40];
    __shared__ alignas(16) __bf16 Bs[48 * 40];
    int tid = threadIdx.x;
    int wv = tid >> 6, l = tid & 63;
    int lr = l & 15, lk = l >> 4;
    int m0 = blockIdx.x * 64;
    f32x4 acc[3];
    f32x4 zero4 = {0.f, 0.f, 0.f, 0.f};
    #pragma unroll
    for (int nt = 0; nt < 3; ++nt) acc[nt] = zero4;

    int ar_ = tid >> 2, aq = tid & 3;
    for (int k0 = 0; k0 < 128; k0 += 32) {
        {
            int m = m0 + ar_;
            uint4 av = make_uint4(0, 0, 0, 0);
            if (m < M) av = *reinterpret_cast<const uint4*>(&A[(size_t)m * 128 + k0 + aq * 8]);
            *reinterpret_cast<uint4*>(&As[ar_ * 40 + aq * 8]) = av;
        }
        if (tid < 192) {
            int c = tid >> 2, q = tid & 3;
            *reinterpret_cast<uint4*>(&Bs[c * 40 + q * 8]) =
                *reinterpret_cast<const uint4*>(&Wt3[(size_t)c * 128 + k0 + q * 8]);
        }
        __syncthreads();
        bf16x8 af = *reinterpret_cast<const bf16x8*>(&As[(wv * 16 + lr) * 40 + lk * 8]);
        #pragma unroll
        for (int nt = 0; nt < 3; ++nt) {
            bf16x8 bfr = *reinterpret_cast<const bf16x8*>(&Bs[(nt * 16 + lr) * 40 + lk * 8]);
            acc[nt] = __builtin_amdgcn_mfma_f32_16x16x32_bf16(af, bfr, acc[nt], 0, 0, 0);
        }
        __syncthreads();
    }

    float alv[3], arv[3];
    #pragma unroll
    for (int nt = 0; nt < 3; ++nt) {
        int col = nt * 16 + lr;
        alv[nt] = (col < 40) ? al[col] : 0.f;
        arv[nt] = (col < 40) ? arr[col] : 0.f;
    }
    #pragma unroll
    for (int r = 0; r < 4; ++r) {
        int m = m0 + wv * 16 + lk * 4 + r;
        float pel = acc[0][r] * alv[0] + acc[1][r] * alv[1] + acc[2][r] * alv[2];
        float per_ = acc[0][r] * arv[0] + acc[1][r] * arv[1] + acc[2][r] * arv[2];
        #pragma unroll
        for (int mk = 1; mk < 16; mk <<= 1) {
            pel  += __shfl_xor(pel, mk);
            per_ += __shfl_xor(per_, mk);
        }
        if (m < M) {
            #pragma unroll
            for (int nt = 0; nt < 3; ++nt) {
                int col = nt * 16 + lr;
                if (col < 40) z40[(size_t)m * 64 + col] = (__bf16)acc[nt][r];
            }
            if (lr == 0) { el3[m] = pel; er3[m] = per_; }
        }
    }
}

// ---------------------------------------------------------------------------
// edge-softmax + aggregation, layers 1-2 (H=4, F=32). One wave per node.
// ---------------------------------------------------------------------------
__global__ __launch_bounds__(256) void gat_agg128w(
    const __bf16* __restrict__ z, const float* __restrict__ el,
    const float* __restrict__ er, const int* __restrict__ rp,
    const ushort* __restrict__ cs, const float* __restrict__ bias,
    __bf16* __restrict__ hout, int n_nodes)
{
    __shared__ uint2 sh[4][4][16];   // [wave][group][edge] = {row elem offset, p}
    int tid = threadIdx.x, w = tid >> 6, t = tid & 63;
    int g = t >> 4, j = t & 15;
    int nd = blockIdx.x * 4 + w;
    if (nd >= n_nodes) return;
    int beg = rp[nd], end = rp[nd + 1];
    float erv = er[nd * 4 + g];
    float m = -3.0e38f, s = 0.f, acc0 = 0.f, acc1 = 0.f;
    const int eoff = g * 32 + 2 * j;

    for (int c0 = beg; c0 < end; c0 += 16) {
        int ch = end - c0; if (ch > 16) ch = 16;
        int chp = (ch + 7) & ~7;
        // ---- phase 1: 16 edge scores per head group ----
        int sidx = (j < ch) ? (int)cs[c0 + j] : 0;
        float e = -3.0e38f;
        if (j < ch) {
            float ev = el[sidx * 4 + g] + erv;
            e = (ev > 0.f) ? ev : 0.2f * ev;
        }
        float cm = e;
        #pragma unroll
        for (int mk = 8; mk; mk >>= 1) cm = fmaxf(cm, __shfl_xor(cm, mk));
        float nm = fmaxf(m, cm);
        float p = (j < ch) ? __expf(e - nm) : 0.f;
        float ps = p;
        #pragma unroll
        for (int mk = 8; mk; mk >>= 1) ps += __shfl_xor(ps, mk);
        float so = __expf(m - nm);
        s = s * so + ps;
        acc0 *= so; acc1 *= so;
        m = nm;
        sh[w][g][j] = make_uint2((unsigned)(sidx << 7), __float_as_uint(p));
        // intra-wave LDS: each group reads only what it wrote -> no barrier
        // ---- phase 2: 8-deep dword gathers (2 bf16 each) ----
        for (int k = 0; k < chp; k += 8) {
            unsigned ld[8]; float pk[8];
            #pragma unroll
            for (int u = 0; u < 8; ++u) {
                uint2 v = sh[w][g][k + u];
                pk[u] = __uint_as_float(v.y);
                ld[u] = *reinterpret_cast<const unsigned*>(&z[(size_t)v.x + eoff]);
            }
            #pragma unroll
            for (int u = 0; u < 8; ++u) {
                float z0 = __uint_as_float(ld[u] << 16);
                float z1 = __uint_as_float(ld[u] & 0xffff0000u);
                acc0 += pk[u] * z0;
                acc1 += pk[u] * z1;
            }
        }
    }
    float o0 = (end > beg) ? acc0 / s : 0.f;
    float o1 = (end > beg) ? acc1 / s : 0.f;
    o0 = fmaxf(o0 + bias[eoff], 0.f);       // relu (layers 1-2)
    o1 = fmaxf(o1 + bias[eoff + 1], 0.f);
    __bf16 t2[2] = {(__bf16)o0, (__bf16)o1};
    *reinterpret_cast<unsigned*>(&hout[(size_t)nd * 128 + eoff]) = *reinterpret_cast<unsigned*>(t2);
}

// ---------------------------------------------------------------------------
// layer-3 aggregation: chunk-parallel, 1 node per wave, + bias + log_softmax
// ---------------------------------------------------------------------------
__global__ __launch_bounds__(256) void gat_agg40c(
    const __bf16* __restrict__ z40, const float* __restrict__ el3,
    const float* __restrict__ er3, const int* __restrict__ rp,
    const ushort* __restrict__ cs, const float* __restrict__ bias,
    float* __restrict__ out, int n_nodes)
{
    __shared__ uint2 sh[4][64];
    int tid = threadIdx.x, wid = tid >> 6, lane = tid & 63;
    int nd = blockIdx.x * 4 + wid;
    if (nd >= n_nodes) return;
    bool act = lane < 40;
    int beg = rp[nd], end = rp[nd + 1];
    float erv = er3[nd];
    float m = -3.0e38f, s = 0.f, acc = 0.f;

    for (int c0 = beg; c0 < end; c0 += 64) {
        int ch = end - c0; if (ch > 64) ch = 64;
        int chp = (ch + 7) & ~7;
        int sidx = (lane < ch) ? (int)cs[c0 + lane] : 0;
        float e = -3.0e38f;
        if (lane < ch) {
            float ev = el3[sidx] + erv;
            e = (ev > 0.f) ? ev : 0.2f * ev;
        }
        float cm = e;
        #pragma unroll
        for (int mk = 32; mk; mk >>= 1) cm = fmaxf(cm, __shfl_xor(cm, mk));
        float nm = fmaxf(m, cm);
        float p = (lane < ch) ? __expf(e - nm) : 0.f;
        float ps = p;
        #pragma unroll
        for (int mk = 32; mk; mk >>= 1) ps += __shfl_xor(ps, mk);
        float so = __expf(m - nm);
        s = s * so + ps;
        acc *= so;
        m = nm;
        sh[wid][lane] = make_uint2((unsigned)(sidx << 6), __float_as_uint(p));
        for (int k = 0; k < chp; k += 8) {
            float zv[8], pk[8];
            #pragma unroll
            for (int u = 0; u < 8; ++u) {
                uint2 v = sh[wid][k + u];
                pk[u] = __uint_as_float(v.y);
                zv[u] = (float)z40[(size_t)v.x + lane];
            }
            #pragma unroll
            for (int u = 0; u < 8; ++u) acc += pk[u] * zv[u];
        }
    }
    float o = (end > beg) ? acc / s : 0.f;
    o += act ? bias[lane] : 0.f;
    float v = act ? o : -3.0e38f;
    float mx = v;
    #pragma unroll
    for (int off = 32; off > 0; off >>= 1) mx = fmaxf(mx, __shfl_xor(mx, off));
    float p2 = act ? __expf(o - mx) : 0.f;
    float sum = p2;
    #pragma unroll
    for (int off = 32; off > 0; off >>= 1) sum += __shfl_xor(sum, off);
    if (act) out[(size_t)nd * 40 + lane] = o - mx - __logf(sum);
}

// ---------------------------------------------------------------------------
extern "C" void kernel_launch(void* const* d_in, const int* in_sizes, int n_in,
                              void* d_out, int out_size, void* d_ws, size_t ws_size,
                              hipStream_t stream) {
    const float* features = (const float*)d_in[0];
    const int*   src      = (const int*)d_in[1];
    const int*   dst      = (const int*)d_in[2];
    const float* W1  = (const float*)d_in[3];
    const float* al1 = (const float*)d_in[4];
    const float* ar1 = (const float*)d_in[5];
    const float* b1  = (const float*)d_in[6];
    const float* W2  = (const float*)d_in[7];
    const float* al2 = (const float*)d_in[8];
    const float* ar2 = (const float*)d_in[9];
    const float* b2  = (const float*)d_in[10];
    const float* W3  = (const float*)d_in[11];
    const float* al3 = (const float*)d_in[12];
    const float* ar3 = (const float*)d_in[13];
    const float* b3  = (const float*)d_in[14];
    float* out = (float*)d_out;

    const int N = NNODES, E = NEDGES;
    const int NB = (N + 255) / 256;   // scan blocks = 196

    // workspace layout (bytes)
    char* ws = (char*)d_ws;
    __bf16* z40    = (__bf16*)(ws + 0);            // N*64*2 (layer 3)
    __bf16* Wt3    = (__bf16*)(ws + 6400000);      // 48*128*2
    ushort* slot16 = (ushort*)(ws + 8000000);      // E*2 (CSR build only)
    __bf16* zb     = (__bf16*)(ws + 25600000);     // N*128*2
    __bf16* hb     = (__bf16*)(ws + 38400000);     // N*128*2
    float*  elb    = (float*)(ws + 51200000);      // N*4*4
    float*  erb    = (float*)(ws + 52000000);      // N*4*4
    __bf16* Wt1    = (__bf16*)(ws + 52800000);     // 128*256*2
    __bf16* Wt2    = (__bf16*)(ws + 52865536);     // 128*128*2
    int* row_ptr   = (int*)(ws + 52898304);        // (N+1)*4
    int* cursor    = (int*)(ws + 53098496);        // N*4 (hist counts)
    int* bsum      = (int*)(ws + 53298496);        // 256*4
    ushort* src16  = (ushort*)(ws + 53299520);     // E*2
    ushort* dst16  = (ushort*)(ws + 54899520);     // E*2
    ushort* csr16  = (ushort*)(ws + 56499520);     // E*2 -> ends 58,099,520

    // ---- prep: weight converts + cursor zero (1 launch) ----
    k_prep<<<412, 256, 0, stream>>>(W1, W2, W3, Wt1, Wt2, Wt3, cursor);

    // ---- fused: layer-1 GEMM + hist/slot atomic pass ----
    k_fused_g1h<<<NGB + NHB, 256, 0, stream>>>(features, Wt1, al1, ar1, zb, elb, erb,
                                               src, dst, src16, dst16, slot16, cursor);

    // ---- CSR finish ----
    k_scan1<<<NB, 256, 0, stream>>>(cursor, row_ptr, bsum, N);
    k_scan2<<<1, 256, 0, stream>>>(bsum, &row_ptr[N], NB);
    k_scan3<<<NB, 256, 0, stream>>>(row_ptr, bsum, N);
    k_scatter_ns<<<(E + 255) / 256, 256, 0, stream>>>(src16, dst16, slot16, row_ptr, csr16, E);

    // ---- layer 1 aggregation ----
    gat_agg128w<<<(N + 3) / 4, 256, 0, stream>>>(zb, elb, erb, row_ptr, csr16, b1, hb, N);

    // ---- layer 2 ----
    gemm_mfma_128b<<<(N + 63) / 64, 256, 0, stream>>>(hb, Wt2, al2, ar2, zb, elb, erb, N, 128);
    gat_agg128w<<<(N + 3) / 4, 256, 0, stream>>>(zb, elb, erb, row_ptr, csr16, b2, hb, N);

    // ---- layer 3 ----
    gemm40_mfma<<<(N + 63) / 64, 256, 0, stream>>>(hb, Wt3, al3, ar3, z40, elb, erb, N);
    gat_agg40c<<<(N + 3) / 4, 256, 0, stream>>>(z40, elb, erb, row_ptr, csr16, b3, out, N);

    (void)in_sizes; (void)n_in; (void)out_size; (void)ws_size;
}

// Round 10
// 184.544 us; speedup vs baseline: 1.3312x; 1.1094x over previous
//
#include <hip/hip_runtime.h>
#include <hip/hip_bf16.h>
#include <math.h>

// Problem constants (GAT_66907000537778)
#define NNODES 50000
#define NEDGES 800000
#define FIN 256
#define HID 32
#define HEADS 4
#define OUTS 40
#define HIDDEN 128   // HEADS*HID
#define CH 3200      // edges per sort block (250 * 3200 = 800000 exactly)
#define NSB 250      // sort blocks

typedef __bf16 bf16x8 __attribute__((ext_vector_type(8)));
typedef float  f32x4  __attribute__((ext_vector_type(4)));

// ---------------------------------------------------------------------------
// prep: all weight converts in ONE launch (216 blocks)
// ---------------------------------------------------------------------------
__global__ __launch_bounds__(256) void k_prep(
    const float* __restrict__ W1, const float* __restrict__ W2,
    const float* __restrict__ W3, __bf16* __restrict__ Wt1,
    __bf16* __restrict__ Wt2, __bf16* __restrict__ Wt3) {
    int b = blockIdx.x, t = threadIdx.x;
    if (b < 128) {                 // W1 [256][128] -> Wt1 [128][256]
        int i = b * 256 + t;
        int k = i >> 7, c = i & 127;
        Wt1[(size_t)c * 256 + k] = (__bf16)W1[i];
    } else if (b < 192) {          // W2 [128][128] -> Wt2 [128][128]
        int i = (b - 128) * 256 + t;
        int k = i >> 7, c = i & 127;
        Wt2[(size_t)c * 128 + k] = (__bf16)W2[i];
    } else {                       // W3 [128][40] -> Wt3 [48][128], rows 40..47 zero
        int i = (b - 192) * 256 + t;
        int c = i >> 7, k = i & 127;
        Wt3[(size_t)c * 128 + k] = (c < 40) ? (__bf16)W3[(size_t)k * 40 + c] : (__bf16)0.f;
    }
}

// ---------------------------------------------------------------------------
// atomic-free CSR: bucket sort by dst>>8, then per-bucket counting sort.
// ---------------------------------------------------------------------------
// stage 1: pack keys + per-(bin,block) histogram (LDS atomics only)
__global__ __launch_bounds__(256) void rs_hist(
    const int* __restrict__ src, const int* __restrict__ dst,
    unsigned* __restrict__ keysA, int* __restrict__ gh, int n) {
    __shared__ int lh[256];
    int t = threadIdx.x, b = blockIdx.x;
    lh[t] = 0;
    __syncthreads();
    int i0 = b * CH, i1 = i0 + CH; if (i1 > n) i1 = n;
    for (int i = i0 + t; i < i1; i += 256) {
        int d = dst[i];
        keysA[i] = ((unsigned)d << 16) | (unsigned)(src[i] & 0xffff);
        atomicAdd(&lh[d >> 8], 1);
    }
    __syncthreads();
    gh[t * NSB + b] = lh[t];   // bin-major layout
}

// stage 3: scatter into contiguous bucket regions (order within bucket free)
__global__ __launch_bounds__(256) void rs_scatter1(
    const unsigned* __restrict__ keysA, unsigned* __restrict__ keysB,
    const int* __restrict__ ghs, int n) {
    __shared__ int base[256];
    int t = threadIdx.x, b = blockIdx.x;
    base[t] = ghs[t * NSB + b];
    __syncthreads();
    int i0 = b * CH, i1 = i0 + CH; if (i1 > n) i1 = n;
    for (int i = i0 + t; i < i1; i += 256) {
        unsigned v = keysA[i];
        int bin = v >> 24;           // dst >> 8
        int pos = atomicAdd(&base[bin], 1);
        keysB[pos] = v;
    }
}

// stage 4: per-bucket counting sort -> row_ptr + csr16 (one block per bucket)
__global__ __launch_bounds__(256) void rs_bucket(
    const unsigned* __restrict__ keysB, const int* __restrict__ ghs,
    ushort* __restrict__ csr16, int* __restrict__ rp, int n) {
    __shared__ int cnt[256];
    __shared__ int ws[4];
    int t = threadIdx.x, hb = blockIdx.x;
    int start = ghs[hb * NSB];
    int end = (hb == 255) ? n : ghs[(hb + 1) * NSB];
    cnt[t] = 0;
    __syncthreads();
    for (int i = start + t; i < end; i += 256)
        atomicAdd(&cnt[(keysB[i] >> 16) & 255], 1);
    __syncthreads();
    // block-exclusive scan of cnt[256]
    int lane = t & 63, w = t >> 6;
    int v = cnt[t];
    int x = v;
    #pragma unroll
    for (int off = 1; off < 64; off <<= 1) {
        int tt = __shfl_up(x, off);
        if (lane >= off) x += tt;
    }
    if (lane == 63) ws[w] = x;
    __syncthreads();
    int woff = 0;
    #pragma unroll
    for (int k = 0; k < 4; ++k) woff += (k < w) ? ws[k] : 0;
    int excl = x - v + woff;
    // row_ptr (node <= NNODES covers rp[NNODES] = E via bucket 195 identity)
    int node = hb * 256 + t;
    if (node <= NNODES) rp[node] = start + excl;
    __syncthreads();
    cnt[t] = excl;   // running within-bucket cursor
    __syncthreads();
    for (int i = start + t; i < end; i += 256) {
        unsigned v2 = keysB[i];
        int j = (v2 >> 16) & 255;
        int pos = start + atomicAdd(&cnt[j], 1);
        csr16[pos] = (ushort)(v2 & 0xffffu);
    }
}

// ---------------------------------------------------------------------------
// scans (generic, reused for the 64000-entry gh matrix)
// ---------------------------------------------------------------------------
__global__ __launch_bounds__(256) void k_scan1(const int* __restrict__ counts,
                                               int* __restrict__ pre,
                                               int* __restrict__ bsum, int n) {
    __shared__ int ws[4];
    int t = threadIdx.x, b = blockIdx.x, i = b * 256 + t;
    int lane = t & 63, w = t >> 6;
    int v = (i < n) ? counts[i] : 0;
    int x = v;
    #pragma unroll
    for (int off = 1; off < 64; off <<= 1) {
        int tt = __shfl_up(x, off);
        if (lane >= off) x += tt;
    }
    if (lane == 63) ws[w] = x;
    __syncthreads();
    int woff = 0;
    #pragma unroll
    for (int k = 0; k < 4; ++k) woff += (k < w) ? ws[k] : 0;
    int excl = x - v + woff;
    if (i < n) pre[i] = excl;
    if (t == 255) bsum[b] = excl + v;
}

__global__ __launch_bounds__(256) void k_scan2(int* __restrict__ bsum,
                                               int* __restrict__ tot, int nb) {
    __shared__ int ws[4];
    int t = threadIdx.x;
    int lane = t & 63, w = t >> 6;
    int v = (t < nb) ? bsum[t] : 0;
    int x = v;
    #pragma unroll
    for (int off = 1; off < 64; off <<= 1) {
        int tt = __shfl_up(x, off);
        if (lane >= off) x += tt;
    }
    if (lane == 63) ws[w] = x;
    __syncthreads();
    int woff = 0;
    #pragma unroll
    for (int k = 0; k < 4; ++k) woff += (k < w) ? ws[k] : 0;
    int excl = x - v + woff;
    __syncthreads();
    if (t < nb) bsum[t] = excl;
    if (t == 255) *tot = excl + v;
}

__global__ __launch_bounds__(256) void k_scan3(int* __restrict__ pre,
                                               const int* __restrict__ bsum, int n) {
    int i = blockIdx.x * 256 + threadIdx.x;
    if (i < n) pre[i] += bsum[i >> 8];
}

// ---------------------------------------------------------------------------
// MFMA bf16 GEMM, N=128, fused attention-score epilogue.
// AF32: A is fp32 (converted during LDS staging); else bf16.
// ---------------------------------------------------------------------------
template<bool AF32>
__global__ __launch_bounds__(256) void gemm_mfma_128(
    const void* __restrict__ Av, const __bf16* __restrict__ Wt,
    const float* __restrict__ al, const float* __restrict__ ar,
    __bf16* __restrict__ z, float* __restrict__ el, float* __restrict__ er,
    int M, int K)
{
    __shared__ alignas(16) __bf16 As[64 * 40];
    __shared__ alignas(16) __bf16 Bs[128 * 40];
    int tid = threadIdx.x;
    int wv = tid >> 6, l = tid & 63;
    int lr = l & 15, lk = l >> 4;
    int m0 = blockIdx.x * 64;
    f32x4 acc[8];
    f32x4 zero4 = {0.f, 0.f, 0.f, 0.f};
    #pragma unroll
    for (int nt = 0; nt < 8; ++nt) acc[nt] = zero4;

    int ar_ = tid >> 2, aq = tid & 3;
    for (int k0 = 0; k0 < K; k0 += 32) {
        {   // A tile: 64 x 32 bf16
            int m = m0 + ar_;
            if constexpr (AF32) {
                const float* A = (const float*)Av;
                __bf16 t8[8] = {};
                if (m < M) {
                    const float4* p = reinterpret_cast<const float4*>(&A[(size_t)m * K + k0 + aq * 8]);
                    float4 a = p[0], b = p[1];
                    t8[0] = (__bf16)a.x; t8[1] = (__bf16)a.y; t8[2] = (__bf16)a.z; t8[3] = (__bf16)a.w;
                    t8[4] = (__bf16)b.x; t8[5] = (__bf16)b.y; t8[6] = (__bf16)b.z; t8[7] = (__bf16)b.w;
                }
                *reinterpret_cast<uint4*>(&As[ar_ * 40 + aq * 8]) = *reinterpret_cast<uint4*>(t8);
            } else {
                const __bf16* A = (const __bf16*)Av;
                uint4 av = make_uint4(0, 0, 0, 0);
                if (m < M) av = *reinterpret_cast<const uint4*>(&A[(size_t)m * K + k0 + aq * 8]);
                *reinterpret_cast<uint4*>(&As[ar_ * 40 + aq * 8]) = av;
            }
        }
        {   // B tile: Wt rows (col-major W): 128 x 32 bf16
            #pragma unroll
            for (int t = 0; t < 2; ++t) {
                int cid = tid + t * 256;
                int c = cid >> 2, q = cid & 3;
                *reinterpret_cast<uint4*>(&Bs[c * 40 + q * 8]) =
                    *reinterpret_cast<const uint4*>(&Wt[(size_t)c * K + k0 + q * 8]);
            }
        }
        __syncthreads();
        bf16x8 af = *reinterpret_cast<const bf16x8*>(&As[(wv * 16 + lr) * 40 + lk * 8]);
        #pragma unroll
        for (int nt = 0; nt < 8; ++nt) {
            bf16x8 bfr = *reinterpret_cast<const bf16x8*>(&Bs[(nt * 16 + lr) * 40 + lk * 8]);
            acc[nt] = __builtin_amdgcn_mfma_f32_16x16x32_bf16(af, bfr, acc[nt], 0, 0, 0);
        }
        __syncthreads();
    }

    float alv[8], arv[8];
    #pragma unroll
    for (int nt = 0; nt < 8; ++nt) {
        alv[nt] = al[nt * 16 + lr];
        arv[nt] = ar[nt * 16 + lr];
    }
    #pragma unroll
    for (int r = 0; r < 4; ++r) {
        int m = m0 + wv * 16 + lk * 4 + r;   // C/D: row=(lane>>4)*4+reg, col=lane&15
        float pel[4], per_[4];
        #pragma unroll
        for (int h = 0; h < 4; ++h) {
            pel[h]  = acc[2 * h][r] * alv[2 * h] + acc[2 * h + 1][r] * alv[2 * h + 1];
            per_[h] = acc[2 * h][r] * arv[2 * h] + acc[2 * h + 1][r] * arv[2 * h + 1];
        }
        #pragma unroll
        for (int mk = 1; mk < 16; mk <<= 1) {
            #pragma unroll
            for (int h = 0; h < 4; ++h) {
                pel[h]  += __shfl_xor(pel[h], mk);
                per_[h] += __shfl_xor(per_[h], mk);
            }
        }
        if (m < M) {
            #pragma unroll
            for (int nt = 0; nt < 8; ++nt)
                z[(size_t)m * 128 + nt * 16 + lr] = (__bf16)acc[nt][r];
            if (lr == 0) {
                #pragma unroll
                for (int h = 0; h < 4; ++h) {
                    el[m * 4 + h] = pel[h];
                    er[m * 4 + h] = per_[h];
                }
            }
        }
    }
}

// ---------------------------------------------------------------------------
// layer-3 MFMA GEMM: z40[M,40(pad64)] = A[M,128] * W3[128,40], fused el3/er3.
// ---------------------------------------------------------------------------
__global__ __launch_bounds__(256) void gemm40_mfma(
    const __bf16* __restrict__ A, const __bf16* __restrict__ Wt3,
    const float* __restrict__ al, const float* __restrict__ arr,
    __bf16* __restrict__ z40, float* __restrict__ el3, float* __restrict__ er3,
    int M)
{
    __shared__ alignas(16) __bf16 As[64 * 40];
    __shared__ alignas(16) __bf16 Bs[48 * 40];
    int tid = threadIdx.x;
    int wv = tid >> 6, l = tid & 63;
    int lr = l & 15, lk = l >> 4;
    int m0 = blockIdx.x * 64;
    f32x4 acc[3];
    f32x4 zero4 = {0.f, 0.f, 0.f, 0.f};
    #pragma unroll
    for (int nt = 0; nt < 3; ++nt) acc[nt] = zero4;

    int ar_ = tid >> 2, aq = tid & 3;
    for (int k0 = 0; k0 < 128; k0 += 32) {
        {
            int m = m0 + ar_;
            uint4 av = make_uint4(0, 0, 0, 0);
            if (m < M) av = *reinterpret_cast<const uint4*>(&A[(size_t)m * 128 + k0 + aq * 8]);
            *reinterpret_cast<uint4*>(&As[ar_ * 40 + aq * 8]) = av;
        }
        if (tid < 192) {
            int c = tid >> 2, q = tid & 3;
            *reinterpret_cast<uint4*>(&Bs[c * 40 + q * 8]) =
                *reinterpret_cast<const uint4*>(&Wt3[(size_t)c * 128 + k0 + q * 8]);
        }
        __syncthreads();
        bf16x8 af = *reinterpret_cast<const bf16x8*>(&As[(wv * 16 + lr) * 40 + lk * 8]);
        #pragma unroll
        for (int nt = 0; nt < 3; ++nt) {
            bf16x8 bfr = *reinterpret_cast<const bf16x8*>(&Bs[(nt * 16 + lr) * 40 + lk * 8]);
            acc[nt] = __builtin_amdgcn_mfma_f32_16x16x32_bf16(af, bfr, acc[nt], 0, 0, 0);
        }
        __syncthreads();
    }

    float alv[3], arv[3];
    #pragma unroll
    for (int nt = 0; nt < 3; ++nt) {
        int col = nt * 16 + lr;
        alv[nt] = (col < 40) ? al[col] : 0.f;
        arv[nt] = (col < 40) ? arr[col] : 0.f;
    }
    #pragma unroll
    for (int r = 0; r < 4; ++r) {
        int m = m0 + wv * 16 + lk * 4 + r;
        float pel = acc[0][r] * alv[0] + acc[1][r] * alv[1] + acc[2][r] * alv[2];
        float per_ = acc[0][r] * arv[0] + acc[1][r] * arv[1] + acc[2][r] * arv[2];
        #pragma unroll
        for (int mk = 1; mk < 16; mk <<= 1) {
            pel  += __shfl_xor(pel, mk);
            per_ += __shfl_xor(per_, mk);
        }
        if (m < M) {
            #pragma unroll
            for (int nt = 0; nt < 3; ++nt) {
                int col = nt * 16 + lr;
                if (col < 40) z40[(size_t)m * 64 + col] = (__bf16)acc[nt][r];
            }
            if (lr == 0) { el3[m] = pel; er3[m] = per_; }
        }
    }
}

// ---------------------------------------------------------------------------
// edge-softmax + aggregation, layers 1-2 (H=4, F=32). One wave per node.
// ---------------------------------------------------------------------------
__global__ __launch_bounds__(256) void gat_agg128w(
    const __bf16* __restrict__ z, const float* __restrict__ el,
    const float* __restrict__ er, const int* __restrict__ rp,
    const ushort* __restrict__ cs, const float* __restrict__ bias,
    __bf16* __restrict__ hout, int n_nodes)
{
    __shared__ uint2 sh[4][4][16];   // [wave][group][edge] = {row elem offset, p}
    int tid = threadIdx.x, w = tid >> 6, t = tid & 63;
    int g = t >> 4, j = t & 15;
    int nd = blockIdx.x * 4 + w;
    if (nd >= n_nodes) return;
    int beg = rp[nd], end = rp[nd + 1];
    float erv = er[nd * 4 + g];
    float m = -3.0e38f, s = 0.f, acc0 = 0.f, acc1 = 0.f;
    const int eoff = g * 32 + 2 * j;

    for (int c0 = beg; c0 < end; c0 += 16) {
        int ch = end - c0; if (ch > 16) ch = 16;
        int chp = (ch + 7) & ~7;
        // ---- phase 1: 16 edge scores per head group ----
        int sidx = (j < ch) ? (int)cs[c0 + j] : 0;
        float e = -3.0e38f;
        if (j < ch) {
            float ev = el[sidx * 4 + g] + erv;
            e = (ev > 0.f) ? ev : 0.2f * ev;
        }
        float cm = e;
        #pragma unroll
        for (int mk = 8; mk; mk >>= 1) cm = fmaxf(cm, __shfl_xor(cm, mk));
        float nm = fmaxf(m, cm);
        float p = (j < ch) ? __expf(e - nm) : 0.f;
        float ps = p;
        #pragma unroll
        for (int mk = 8; mk; mk >>= 1) ps += __shfl_xor(ps, mk);
        float so = __expf(m - nm);
        s = s * so + ps;
        acc0 *= so; acc1 *= so;
        m = nm;
        sh[w][g][j] = make_uint2((unsigned)(sidx << 7), __float_as_uint(p));
        // intra-wave LDS: each group reads only what it wrote -> no barrier
        // ---- phase 2: 8-deep dword gathers (2 bf16 each) ----
        for (int k = 0; k < chp; k += 8) {
            unsigned ld[8]; float pk[8];
            #pragma unroll
            for (int u = 0; u < 8; ++u) {
                uint2 v = sh[w][g][k + u];
                pk[u] = __uint_as_float(v.y);
                ld[u] = *reinterpret_cast<const unsigned*>(&z[(size_t)v.x + eoff]);
            }
            #pragma unroll
            for (int u = 0; u < 8; ++u) {
                float z0 = __uint_as_float(ld[u] << 16);
                float z1 = __uint_as_float(ld[u] & 0xffff0000u);
                acc0 += pk[u] * z0;
                acc1 += pk[u] * z1;
            }
        }
    }
    float o0 = (end > beg) ? acc0 / s : 0.f;
    float o1 = (end > beg) ? acc1 / s : 0.f;
    o0 = fmaxf(o0 + bias[eoff], 0.f);       // relu (layers 1-2)
    o1 = fmaxf(o1 + bias[eoff + 1], 0.f);
    __bf16 t2[2] = {(__bf16)o0, (__bf16)o1};
    *reinterpret_cast<unsigned*>(&hout[(size_t)nd * 128 + eoff]) = *reinterpret_cast<unsigned*>(t2);
}

// ---------------------------------------------------------------------------
// layer-3 aggregation: chunk-parallel, 1 node per wave, + bias + log_softmax
// ---------------------------------------------------------------------------
__global__ __launch_bounds__(256) void gat_agg40c(
    const __bf16* __restrict__ z40, const float* __restrict__ el3,
    const float* __restrict__ er3, const int* __restrict__ rp,
    const ushort* __restrict__ cs, const float* __restrict__ bias,
    float* __restrict__ out, int n_nodes)
{
    __shared__ uint2 sh[4][64];
    int tid = threadIdx.x, wid = tid >> 6, lane = tid & 63;
    int nd = blockIdx.x * 4 + wid;
    if (nd >= n_nodes) return;
    bool act = lane < 40;
    int beg = rp[nd], end = rp[nd + 1];
    float erv = er3[nd];
    float m = -3.0e38f, s = 0.f, acc = 0.f;

    for (int c0 = beg; c0 < end; c0 += 64) {
        int ch = end - c0; if (ch > 64) ch = 64;
        int chp = (ch + 7) & ~7;
        int sidx = (lane < ch) ? (int)cs[c0 + lane] : 0;
        float e = -3.0e38f;
        if (lane < ch) {
            float ev = el3[sidx] + erv;
            e = (ev > 0.f) ? ev : 0.2f * ev;
        }
        float cm = e;
        #pragma unroll
        for (int mk = 32; mk; mk >>= 1) cm = fmaxf(cm, __shfl_xor(cm, mk));
        float nm = fmaxf(m, cm);
        float p = (lane < ch) ? __expf(e - nm) : 0.f;
        float ps = p;
        #pragma unroll
        for (int mk = 32; mk; mk >>= 1) ps += __shfl_xor(ps, mk);
        float so = __expf(m - nm);
        s = s * so + ps;
        acc *= so;
        m = nm;
        sh[wid][lane] = make_uint2((unsigned)(sidx << 6), __float_as_uint(p));
        for (int k = 0; k < chp; k += 8) {
            float zv[8], pk[8];
            #pragma unroll
            for (int u = 0; u < 8; ++u) {
                uint2 v = sh[wid][k + u];
                pk[u] = __uint_as_float(v.y);
                zv[u] = (float)z40[(size_t)v.x + lane];
            }
            #pragma unroll
            for (int u = 0; u < 8; ++u) acc += pk[u] * zv[u];
        }
    }
    float o = (end > beg) ? acc / s : 0.f;
    o += act ? bias[lane] : 0.f;
    float v = act ? o : -3.0e38f;
    float mx = v;
    #pragma unroll
    for (int off = 32; off > 0; off >>= 1) mx = fmaxf(mx, __shfl_xor(mx, off));
    float p2 = act ? __expf(o - mx) : 0.f;
    float sum = p2;
    #pragma unroll
    for (int off = 32; off > 0; off >>= 1) sum += __shfl_xor(sum, off);
    if (act) out[(size_t)nd * 40 + lane] = o - mx - __logf(sum);
}

// ---------------------------------------------------------------------------
extern "C" void kernel_launch(void* const* d_in, const int* in_sizes, int n_in,
                              void* d_out, int out_size, void* d_ws, size_t ws_size,
                              hipStream_t stream) {
    const float* features = (const float*)d_in[0];
    const int*   src      = (const int*)d_in[1];
    const int*   dst      = (const int*)d_in[2];
    const float* W1  = (const float*)d_in[3];
    const float* al1 = (const float*)d_in[4];
    const float* ar1 = (const float*)d_in[5];
    const float* b1  = (const float*)d_in[6];
    const float* W2  = (const float*)d_in[7];
    const float* al2 = (const float*)d_in[8];
    const float* ar2 = (const float*)d_in[9];
    const float* b2  = (const float*)d_in[10];
    const float* W3  = (const float*)d_in[11];
    const float* al3 = (const float*)d_in[12];
    const float* ar3 = (const float*)d_in[13];
    const float* b3  = (const float*)d_in[14];
    float* out = (float*)d_out;

    const int N = NNODES, E = NEDGES;
    const int NGH = 256 * NSB;        // 64000 hist entries
    const int NBG = (NGH + 255) / 256; // 250 scan blocks

    // workspace layout (bytes)
    char* ws = (char*)d_ws;
    __bf16* z40    = (__bf16*)(ws + 0);            // N*64*2 (layer 3)
    __bf16* Wt3    = (__bf16*)(ws + 6400000);      // 48*128*2
    unsigned* keysB = (unsigned*)(ws + 8000000);   // E*4 (sort ping)
    int* gh        = (int*)(ws + 12000000);        // 64000*4 + spare
    int* ghs       = (int*)(ws + 12400000);        // 64000*4
    __bf16* zb     = (__bf16*)(ws + 25600000);     // N*128*2
    __bf16* hb     = (__bf16*)(ws + 38400000);     // N*128*2
    float*  elb    = (float*)(ws + 51200000);      // N*4*4
    float*  erb    = (float*)(ws + 52000000);      // N*4*4
    __bf16* Wt1    = (__bf16*)(ws + 52800000);     // 128*256*2
    __bf16* Wt2    = (__bf16*)(ws + 52865536);     // 128*128*2
    int* row_ptr   = (int*)(ws + 52898304);        // (N+1)*4
    int* bsum      = (int*)(ws + 53298496);        // 256*4
    unsigned* keysA = (unsigned*)(ws + 53299520);  // E*4 (ends 56,499,520)
    ushort* csr16  = (ushort*)(ws + 56499520);     // E*2 -> ends 58,099,520

    // ---- prep: weight converts (1 launch) ----
    k_prep<<<216, 256, 0, stream>>>(W1, W2, W3, Wt1, Wt2, Wt3);

    // ---- atomic-free CSR build: bucket sort ----
    rs_hist<<<NSB, 256, 0, stream>>>(src, dst, keysA, gh, E);
    k_scan1<<<NBG, 256, 0, stream>>>(gh, ghs, bsum, NGH);
    k_scan2<<<1, 256, 0, stream>>>(bsum, &gh[NGH], NBG);
    k_scan3<<<NBG, 256, 0, stream>>>(ghs, bsum, NGH);
    rs_scatter1<<<NSB, 256, 0, stream>>>(keysA, keysB, ghs, E);
    rs_bucket<<<256, 256, 0, stream>>>(keysB, ghs, csr16, row_ptr, E);

    // ---- layer 1 ----
    gemm_mfma_128<true><<<(N + 63) / 64, 256, 0, stream>>>(features, Wt1, al1, ar1, zb, elb, erb, N, 256);
    gat_agg128w<<<(N + 3) / 4, 256, 0, stream>>>(zb, elb, erb, row_ptr, csr16, b1, hb, N);

    // ---- layer 2 ----
    gemm_mfma_128<false><<<(N + 63) / 64, 256, 0, stream>>>(hb, Wt2, al2, ar2, zb, elb, erb, N, 128);
    gat_agg128w<<<(N + 3) / 4, 256, 0, stream>>>(zb, elb, erb, row_ptr, csr16, b2, hb, N);

    // ---- layer 3 ----
    gemm40_mfma<<<(N + 63) / 64, 256, 0, stream>>>(hb, Wt3, al3, ar3, z40, elb, erb, N);
    gat_agg40c<<<(N + 3) / 4, 256, 0, stream>>>(z40, elb, erb, row_ptr, csr16, b3, out, N);

    (void)in_sizes; (void)n_in; (void)out_size; (void)ws_size;
}